// Round 1
// 879.495 us; speedup vs baseline: 1.0747x; 1.0747x over previous
//
#include <hip/hip_runtime.h>
#include <math.h>

#define Bq 8
#define Sq 500
#define Tq 30
#define Dq 5
#define Kq 10
#define Hq 64
#define TWq 512
#define Eq 8000
#define NS (Bq*Sq)      // 4000
#define NTt (NS*Dq)     // 20000
#define G3 (3*Hq)       // 192
#define TG 4            // tweet seqs per block

#define MR 48           // padded GEMM rows (TG*Kq=40 -> 48)
#define KC 64           // K chunk staged per iteration
#define XPITCH 72       // LDS row pitch in bf16 elems (144B: 2-way bank alias = free)
#define XGP 196         // xg fp32 pitch (196%32=4 -> conflict-free epilogue)
#define NKT (TWq/32)    // 16 k-tiles of 32
#define NNT (G3/16)     // 12 n-tiles of 16
#define PSEQ 16         // price seqs per block

#define XROWS 40        // rows of xg actually used (TG*Kq)
#define STG_PLANE (MR*XPITCH)        // 3456 shorts per hi/lo plane
#define STG_BUF  (2*STG_PLANE)       // 6912 shorts per buffer (hi+lo)

typedef __attribute__((ext_vector_type(8))) short short8_t;
typedef __attribute__((ext_vector_type(4))) float float4_t;

__device__ __forceinline__ float fsig(float x) {
    return 1.0f / (1.0f + __expf(-x));
}
__device__ __forceinline__ float ftanh(float x) {
    // 1 - 2/(e^{2x}+1); exact limits at +-inf
    return 1.0f - 2.0f / (__expf(2.0f * x) + 1.0f);
}

__device__ __forceinline__ float wave_sum64(float v) {
    #pragma unroll
    for (int off = 32; off; off >>= 1) v += __shfl_xor(v, off, 64);
    return v;
}

__device__ __forceinline__ short f32_to_bf16_rn(float f) {
    union { float f; unsigned u; } v; v.f = f;
    unsigned r = v.u + 0x7fffu + ((v.u >> 16) & 1u);
    return (short)(r >> 16);
}
__device__ __forceinline__ float bf16_to_f32(short s) {
    union { unsigned u; float f; } v; v.u = ((unsigned)(unsigned short)s) << 16;
    return v.f;
}

// ---- prep: [K x 192] row-major -> MFMA B-frag order, split hi/lo bf16 ------
// Wf[kt][nt][lane][j] = W[kt*32 + (lane>>4)*8 + j][nt*16 + (lane&15)]
// grid = (K/32)*NNT blocks of 64
__global__ __launch_bounds__(64)
void wfrag_prep_kernel(const float* __restrict__ Wi,
                       short* __restrict__ Wf_hi, short* __restrict__ Wf_lo) {
    const int kt = blockIdx.x / NNT;
    const int nt = blockIdx.x - kt*NNT;
    const int lane = threadIdx.x;
    const int quad = lane >> 4, l16 = lane & 15;
    short h[8], l[8];
    #pragma unroll
    for (int j = 0; j < 8; j++) {
        int k = kt*32 + quad*8 + j;
        int n = nt*16 + l16;
        float w = Wi[(size_t)k*G3 + n];
        short hi = f32_to_bf16_rn(w);
        short lo = f32_to_bf16_rn(w - bf16_to_f32(hi));
        h[j] = hi; l[j] = lo;
    }
    size_t off = ((size_t)blockIdx.x*64 + lane)*8;
    *(short8_t*)(Wf_hi + off) = *(const short8_t*)h;
    *(short8_t*)(Wf_lo + off) = *(const short8_t*)l;
}

// ---- prep for bil_A: B[kidx][n] = bil_A[n*4096 + kidx]; grid 128*4 ---------
__global__ __launch_bounds__(64)
void bilfrag_prep_kernel(const float* __restrict__ A,
                         short* __restrict__ Bf_hi, short* __restrict__ Bf_lo) {
    const int kt = blockIdx.x >> 2;        // 0..127
    const int nt = blockIdx.x & 3;         // 0..3
    const int lane = threadIdx.x;
    const int quad = lane >> 4, l16 = lane & 15;
    short h[8], l[8];
    #pragma unroll
    for (int j = 0; j < 8; j++) {
        int kidx = kt*32 + quad*8 + j;
        int n = nt*16 + l16;
        float w = A[(size_t)n*4096 + kidx];
        short hi = f32_to_bf16_rn(w);
        h[j] = hi; l[j] = f32_to_bf16_rn(w - bf16_to_f32(hi));
    }
    size_t off = ((size_t)blockIdx.x*64 + lane)*8;
    *(short8_t*)(Bf_hi + off) = *(const short8_t*)h;
    *(short8_t*)(Bf_lo + off) = *(const short8_t*)l;
}

// -------- price GRU via MFMA: 16 seqs/block, gate-aligned n-tiles -----------
// wave w owns output units u = 16w + (lane&15); gates r/z/n come from
// n-tiles {w, 4+w, 8+w} so r,z,n land in the SAME lane -> no hg LDS trip.
__global__ __launch_bounds__(256)
void price_gru_mfma_kernel(const float* __restrict__ price,
                           const float* __restrict__ Wi,
                           const short* __restrict__ Whf_hi, const short* __restrict__ Whf_lo,
                           const float* __restrict__ bi, const float* __restrict__ bh,
                           float* __restrict__ xout) {
    __shared__ __align__(16) float price_s[PSEQ*90];
    __shared__ __align__(16) short h_hi[PSEQ*72];
    __shared__ __align__(16) short h_lo[PSEQ*72];
    const int tid = threadIdx.x;
    const int n0 = blockIdx.x * PSEQ;
    const int wv = tid >> 6;
    const int lane = tid & 63;
    const int quad = lane >> 4;
    const int l16 = lane & 15;
    const int u = wv*16 + l16;
    for (int i = tid; i < PSEQ*90; i += 256) price_s[i] = price[(size_t)n0*90 + i];
    for (int i = tid; i < PSEQ*72; i += 256) { h_hi[i] = 0; h_lo[i] = 0; }
    float wir[3], wiz[3], win[3];
    #pragma unroll
    for (int k = 0; k < 3; k++) {
        wir[k] = Wi[k*G3 + u];
        wiz[k] = Wi[k*G3 + 64 + u];
        win[k] = Wi[k*G3 + 128 + u];
    }
    const float cbr = bi[u] + bh[u];
    const float cbz = bi[64+u] + bh[64+u];
    const float bin = bi[128+u];
    const float bhn = bh[128+u];
    short8_t bfh[2][3], bfl[2][3];
    #pragma unroll
    for (int kt = 0; kt < 2; kt++)
        #pragma unroll
        for (int g = 0; g < 3; g++) {
            size_t off = (((size_t)kt*NNT + (g*4 + wv))*64 + lane)*8;
            bfh[kt][g] = *(const short8_t*)(Whf_hi + off);
            bfl[kt][g] = *(const short8_t*)(Whf_lo + off);
        }
    float hprev[4] = {0.f,0.f,0.f,0.f}, sum[4] = {0.f,0.f,0.f,0.f};
    __syncthreads();
    for (int t = 0; t < Tq; t++) {
        short8_t ah[2], al[2];
        #pragma unroll
        for (int kt = 0; kt < 2; kt++) {
            int addr = l16*72 + kt*32 + quad*8;
            ah[kt] = *(const short8_t*)&h_hi[addr];
            al[kt] = *(const short8_t*)&h_lo[addr];
        }
        float4_t accr = {0.f,0.f,0.f,0.f}, accz = {0.f,0.f,0.f,0.f}, accn = {0.f,0.f,0.f,0.f};
        #pragma unroll
        for (int kt = 0; kt < 2; kt++) {
            accr = __builtin_amdgcn_mfma_f32_16x16x32_bf16(ah[kt], bfh[kt][0], accr, 0,0,0);
            accr = __builtin_amdgcn_mfma_f32_16x16x32_bf16(ah[kt], bfl[kt][0], accr, 0,0,0);
            accr = __builtin_amdgcn_mfma_f32_16x16x32_bf16(al[kt], bfh[kt][0], accr, 0,0,0);
            accz = __builtin_amdgcn_mfma_f32_16x16x32_bf16(ah[kt], bfh[kt][1], accz, 0,0,0);
            accz = __builtin_amdgcn_mfma_f32_16x16x32_bf16(ah[kt], bfl[kt][1], accz, 0,0,0);
            accz = __builtin_amdgcn_mfma_f32_16x16x32_bf16(al[kt], bfh[kt][1], accz, 0,0,0);
            accn = __builtin_amdgcn_mfma_f32_16x16x32_bf16(ah[kt], bfh[kt][2], accn, 0,0,0);
            accn = __builtin_amdgcn_mfma_f32_16x16x32_bf16(ah[kt], bfl[kt][2], accn, 0,0,0);
            accn = __builtin_amdgcn_mfma_f32_16x16x32_bf16(al[kt], bfh[kt][2], accn, 0,0,0);
        }
        __syncthreads();   // A-frag reads done before h is rewritten
        #pragma unroll
        for (int r = 0; r < 4; r++) {
            const int s = quad*4 + r;
            float p0 = price_s[s*90 + t*3 + 0];
            float p1 = price_s[s*90 + t*3 + 1];
            float p2 = price_s[s*90 + t*3 + 2];
            float xr = fmaf(p2, wir[2], fmaf(p1, wir[1], fmaf(p0, wir[0], cbr)));
            float xz = fmaf(p2, wiz[2], fmaf(p1, wiz[1], fmaf(p0, wiz[0], cbz)));
            float xn = fmaf(p2, win[2], fmaf(p1, win[1], fmaf(p0, win[0], bin)));
            float rg = fsig(xr + accr[r]);
            float zg = fsig(xz + accz[r]);
            float ng = ftanh(xn + rg*(accn[r] + bhn));
            float h = (1.0f - zg)*ng + zg*hprev[r];
            hprev[r] = h; sum[r] += h;
            short hh = f32_to_bf16_rn(h);
            h_hi[s*72 + u] = hh;
            h_lo[s*72 + u] = f32_to_bf16_rn(h - bf16_to_f32(hh));
        }
        __syncthreads();   // h writes visible before next A-frag read
    }
    #pragma unroll
    for (int r = 0; r < 4; r++)
        xout[(size_t)(n0 + quad*4 + r)*Hq + u] = sum[r];
}

// ------------- tweet GRU: MFMA split-bf16 projection + fp32 recurrence ------
// v2: 40-row xg (LDS 41984->35.5KB => 4 blocks/CU), double-buffered staging
// with T14 issue-early/write-late split (16->9 projection barriers), hoisted
// staging descriptors, hg dot spread over 4 waves (48 lanes each), tmax exit.
__global__ __launch_bounds__(256, 4)
void tweet_gru_kernel(const float* __restrict__ tweets,
                      const int* __restrict__ counts,
                      const short* __restrict__ Wf_hi, const short* __restrict__ Wf_lo,
                      const float* __restrict__ Wh,
                      const float* __restrict__ bi, const float* __restrict__ bh,
                      float* __restrict__ news) {
    __shared__ __align__(16) char smem[XROWS*XGP*4];   // 31360 B
    __shared__ __align__(16) float h_s[TG][Hq];        // 1024 B
    __shared__ __align__(16) float hg_s[TG][G3];       // 3072 B
    __shared__ int len_s[TG];
    __shared__ int tmax_s;
    short* stg = (short*)smem;     // [2 bufs][hi 3456 | lo 3456] shorts = 27648 B
    float* xg  = (float*)smem;     // [XROWS][XGP] f32, aliases staging

    const int tid  = threadIdx.x;
    const int n0   = blockIdx.x * TG;
    const int wave = tid >> 6;
    const int lane = tid & 63;
    const int quad = lane >> 4;
    const int l16  = lane & 15;

    if (tid < TG) {
        int c = counts[n0 + tid];
        len_s[tid] = c < 0 ? 0 : (c > Kq ? Kq : c);
    }
    __syncthreads();
    if (tid == 0) {
        int m01 = len_s[0] > len_s[1] ? len_s[0] : len_s[1];
        int m23 = len_s[2] > len_s[3] ? len_s[2] : len_s[3];
        tmax_s = m01 > m23 ? m01 : m23;
    }

    // ---- hoisted staging descriptors (640 float4 items, stride 256) --------
    const float* gp[3];
    int lofs[3];
    bool val[3];
    #pragma unroll
    for (int j = 0; j < 3; j++) {
        const int ii = tid + j*256;
        const bool ok = ii < TG*Kq*(KC/4);        // < 640
        const int i = ok ? ii : 0;
        const int row = i >> 4;
        const int c4  = i & 15;
        const int s   = (row*205) >> 11;          // row/10 for row<48
        const int t   = row - s*10;
        val[j]  = ok && (t < len_s[s]);
        gp[j]   = tweets + (((size_t)(n0+s))*Kq + t)*TWq + c4*4;
        lofs[j] = row*XPITCH + c4*4;
    }

    float4_t acc[3][3];   // [mt][ntl]
    #pragma unroll
    for (int a = 0; a < 3; a++)
        #pragma unroll
        for (int b = 0; b < 3; b++)
            acc[a][b] = (float4_t){0.f, 0.f, 0.f, 0.f};

    // ---- prologue: stage chunk 0 into buffer 0 ----
    #pragma unroll
    for (int j = 0; j < 3; j++) if (val[j]) {
        float4 v = *(const float4*)(gp[j]);
        float f[4] = {v.x, v.y, v.z, v.w};
        short hh[4], ll[4];
        #pragma unroll
        for (int q = 0; q < 4; q++) {
            short hi = f32_to_bf16_rn(f[q]);
            hh[q] = hi;
            ll[q] = f32_to_bf16_rn(f[q] - bf16_to_f32(hi));
        }
        *(short4*)&stg[lofs[j]]             = *(const short4*)hh;
        *(short4*)&stg[STG_PLANE + lofs[j]] = *(const short4*)ll;
    }
    __syncthreads();

    for (int ch = 0; ch < TWq/KC; ch++) {
        const int cur = ch & 1;
        // (1) issue next chunk's global loads early (latency hides under MFMA)
        float4 v[3];
        if (ch < TWq/KC - 1) {
            #pragma unroll
            for (int j = 0; j < 3; j++) if (val[j])
                v[j] = *(const float4*)(gp[j] + (ch+1)*KC);
        }
        // (2) MFMA on current buffer
        const short* xh = stg + cur*STG_BUF;
        const short* xl = xh + STG_PLANE;
        #pragma unroll
        for (int ks = 0; ks < KC/32; ks++) {
            const int kt = ch*(KC/32) + ks;
            short8_t bh_[3], bl_[3];
            #pragma unroll
            for (int ntl = 0; ntl < 3; ntl++) {
                size_t off = (((size_t)kt*NNT + (wave*3 + ntl))*64 + lane)*8;
                bh_[ntl] = *(const short8_t*)(Wf_hi + off);
                bl_[ntl] = *(const short8_t*)(Wf_lo + off);
            }
            short8_t ah_[3], al_[3];
            #pragma unroll
            for (int mt = 0; mt < 3; mt++) {
                int addr = (mt*16 + l16)*XPITCH + ks*32 + quad*8;
                ah_[mt] = *(const short8_t*)&xh[addr];
                al_[mt] = *(const short8_t*)&xl[addr];
            }
            #pragma unroll
            for (int mt = 0; mt < 3; mt++)
                #pragma unroll
                for (int ntl = 0; ntl < 3; ntl++) {
                    acc[mt][ntl] = __builtin_amdgcn_mfma_f32_16x16x32_bf16(ah_[mt], bh_[ntl], acc[mt][ntl], 0, 0, 0);
                    acc[mt][ntl] = __builtin_amdgcn_mfma_f32_16x16x32_bf16(ah_[mt], bl_[ntl], acc[mt][ntl], 0, 0, 0);
                    acc[mt][ntl] = __builtin_amdgcn_mfma_f32_16x16x32_bf16(al_[mt], bh_[ntl], acc[mt][ntl], 0, 0, 0);
                }
        }
        // (3) convert + write next chunk into the other buffer
        if (ch < TWq/KC - 1) {
            short* yh = stg + (cur^1)*STG_BUF;
            short* yl = yh + STG_PLANE;
            #pragma unroll
            for (int j = 0; j < 3; j++) if (val[j]) {
                float f[4] = {v[j].x, v[j].y, v[j].z, v[j].w};
                short hh[4], ll[4];
                #pragma unroll
                for (int q = 0; q < 4; q++) {
                    short hi = f32_to_bf16_rn(f[q]);
                    hh[q] = hi;
                    ll[q] = f32_to_bf16_rn(f[q] - bf16_to_f32(hi));
                }
                *(short4*)&yh[lofs[j]] = *(const short4*)hh;
                *(short4*)&yl[lofs[j]] = *(const short4*)ll;
            }
        }
        __syncthreads();   // next buffer ready; current buffer reads done
    }

    // ---- epilogue: acc -> xg (only the 40 live rows) ----
    #pragma unroll
    for (int ntl = 0; ntl < 3; ntl++) {
        const int col = (wave*3 + ntl)*16 + l16;
        const float bic = bi[col];
        #pragma unroll
        for (int mt = 0; mt < 3; mt++) {
            const int row0 = mt*16 + quad*4;
            if (row0 < XROWS) {
                #pragma unroll
                for (int r = 0; r < 4; r++)
                    xg[(row0 + r)*XGP + col] = acc[mt][ntl][r] + bic;
            }
        }
    }
    // ---- recurrence (fp32): hg dot over 4 waves x 48 lanes ----
    const int gcol = wave*48 + (lane & 63);
    const bool gact = lane < 48;
    float w[Hq];
    if (gact) {
        #pragma unroll
        for (int j = 0; j < Hq; j++) w[j] = Wh[(size_t)j*G3 + gcol];
    }
    const float bhg = gact ? bh[gcol] : 0.0f;
    const int su_s = wave;
    const int su_u = lane;
    h_s[su_s][su_u] = 0.0f;
    float hreg = 0.0f, sum = 0.0f;
    __syncthreads();
    const int tmax = tmax_s;
    for (int t = 0; t < tmax; t++) {
        if (gact) {
            #pragma unroll
            for (int s = 0; s < TG; s++) {
                if (t < len_s[s]) {
                    float a0=0.f,a1=0.f,a2=0.f,a3=0.f;
                    #pragma unroll
                    for (int j = 0; j < Hq; j += 4) {
                        float4 hv = *(const float4*)&h_s[s][j];
                        a0 = fmaf(hv.x, w[j+0], a0);
                        a1 = fmaf(hv.y, w[j+1], a1);
                        a2 = fmaf(hv.z, w[j+2], a2);
                        a3 = fmaf(hv.w, w[j+3], a3);
                    }
                    hg_s[s][gcol] = bhg + ((a0+a1)+(a2+a3));
                }
            }
        }
        __syncthreads();
        if (t < len_s[su_s]) {
            const float* xr = &xg[(su_s*Kq + t)*XGP];
            float r  = fsig(xr[su_u]        + hg_s[su_s][su_u]);
            float z  = fsig(xr[Hq+su_u]     + hg_s[su_s][Hq+su_u]);
            float nn = ftanh(xr[2*Hq+su_u] + r*hg_s[su_s][2*Hq+su_u]);
            hreg = (1.0f - z)*nn + z*hreg;
            sum += hreg;
            h_s[su_s][su_u] = hreg;
        }
        __syncthreads();
    }
    news[(size_t)(n0 + su_s)*Hq + su_u] = sum;
}

// ---------------- date GRU: one block (192 thr) per sequence ----------------
__global__ __launch_bounds__(192)
void date_gru_kernel(const float* __restrict__ news,
                     const float* __restrict__ Wi, const float* __restrict__ Wh,
                     const float* __restrict__ bi, const float* __restrict__ bh,
                     float* __restrict__ text) {
    __shared__ __align__(16) float nw_s[Dq*Hq];
    __shared__ __align__(16) float h_s[Hq];
    __shared__ __align__(16) float xg_s[G3];
    __shared__ __align__(16) float hg_s[G3];
    const int n = blockIdx.x;
    const int g = threadIdx.x;
    for (int i = g; i < Dq*Hq; i += 192) nw_s[i] = news[(size_t)n*Dq*Hq + i];
    float wi[Hq], wh[Hq];
    #pragma unroll
    for (int j = 0; j < Hq; j++) { wi[j] = Wi[j*G3+g]; wh[j] = Wh[j*G3+g]; }
    const float big = bi[g], bhg = bh[g];
    if (g < Hq) h_s[g] = 0.0f;
    float hreg = 0.0f, sum = 0.0f;
    __syncthreads();
    for (int t = 0; t < Dq; t++) {
        float a0=0.f,a1=0.f,a2=0.f,a3=0.f, b0=0.f,b1=0.f,b2=0.f,b3=0.f;
        #pragma unroll
        for (int j = 0; j < Hq; j += 4) {
            float4 nv = *(const float4*)&nw_s[t*Hq + j];
            float4 hv = *(const float4*)&h_s[j];
            a0 = fmaf(nv.x, wi[j+0], a0);
            a1 = fmaf(nv.y, wi[j+1], a1);
            a2 = fmaf(nv.z, wi[j+2], a2);
            a3 = fmaf(nv.w, wi[j+3], a3);
            b0 = fmaf(hv.x, wh[j+0], b0);
            b1 = fmaf(hv.y, wh[j+1], b1);
            b2 = fmaf(hv.z, wh[j+2], b2);
            b3 = fmaf(hv.w, wh[j+3], b3);
        }
        xg_s[g] = big + ((a0+a1)+(a2+a3));
        hg_s[g] = bhg + ((b0+b1)+(b2+b3));
        __syncthreads();
        if (g < Hq) {
            float r  = fsig(xg_s[g]      + hg_s[g]);
            float z  = fsig(xg_s[Hq+g]   + hg_s[Hq+g]);
            float nn = ftanh(xg_s[2*Hq+g] + r*hg_s[2*Hq+g]);
            hreg = (1.0f - z)*nn + z*hreg;
            sum += hreg;
            h_s[g] = hreg;
        }
        __syncthreads();
    }
    if (g < Hq) text[(size_t)n*Hq + g] = sum;
}

// -------- bilinear via MFMA: C[n,k] = tanh(sum_ij P[n,ij] A2[k,ij] + b_k) ---
#define TP 68
#define XP 72
__global__ __launch_bounds__(256)
void bilinear_mfma_kernel(const float* __restrict__ text, const float* __restrict__ x,
                          const short* __restrict__ Bf_hi, const short* __restrict__ Bf_lo,
                          const float* __restrict__ bb, float* __restrict__ ft) {
    __shared__ __align__(16) float t_s[16*TP];
    __shared__ __align__(16) float x_s[16*XP];
    const int tid = threadIdx.x;
    const int n0 = blockIdx.x * 16;
    const int wv = tid >> 6, lane = tid & 63, quad = lane >> 4, l16 = lane & 15;
    for (int i = tid; i < 16*64; i += 256) {
        int r = i >> 6, c = i & 63;
        t_s[r*TP + c] = text[(size_t)(n0 + r)*Hq + c];
        x_s[r*XP + c] = x[(size_t)(n0 + r)*Hq + c];
    }
    float4_t acc = {0.f,0.f,0.f,0.f};
    __syncthreads();
    for (int kt = 0; kt < 128; kt++) {
        const int i  = kt >> 1;
        const int j0 = (kt & 1)*32 + quad*8;
        size_t boff = (((size_t)kt*4 + wv)*64 + lane)*8;
        short8_t bh_ = *(const short8_t*)(Bf_hi + boff);
        short8_t bl_ = *(const short8_t*)(Bf_lo + boff);
        float ti = t_s[l16*TP + i];
        float xv[8];
        *(float4*)&xv[0] = *(const float4*)&x_s[l16*XP + j0];
        *(float4*)&xv[4] = *(const float4*)&x_s[l16*XP + j0 + 4];
        short ph[8], pl[8];
        #pragma unroll
        for (int jj = 0; jj < 8; jj++) {
            float p = ti * xv[jj];
            short hi = f32_to_bf16_rn(p);
            ph[jj] = hi;
            pl[jj] = f32_to_bf16_rn(p - bf16_to_f32(hi));
        }
        short8_t ah = *(const short8_t*)ph;
        short8_t al = *(const short8_t*)pl;
        acc = __builtin_amdgcn_mfma_f32_16x16x32_bf16(ah, bh_, acc, 0,0,0);
        acc = __builtin_amdgcn_mfma_f32_16x16x32_bf16(ah, bl_, acc, 0,0,0);
        acc = __builtin_amdgcn_mfma_f32_16x16x32_bf16(al, bh_, acc, 0,0,0);
    }
    const int col = wv*16 + l16;
    const float bk = bb[col];
    #pragma unroll
    for (int r = 0; r < 4; r++) {
        int n = quad*4 + r;
        ft[(size_t)(n0 + n)*Hq + col] = ftanh(acc[r] + bk);
    }
}

// ----------------------------- GNN ------------------------------------------
__global__ void deg_kernel(const int* __restrict__ ei, float* __restrict__ deg) {
    int e = blockIdx.x*256 + threadIdx.x;
    if (e < Eq) atomicAdd(&deg[ei[Eq + e]], 1.0f);
}

__global__ void agg_kernel(const int* __restrict__ ei, const float* __restrict__ ft,
                           float* __restrict__ agg) {
    int gid = blockIdx.x*256 + threadIdx.x;
    int e = gid >> 6;
    int u = gid & 63;
    if (e < Eq) {
        int src = ei[e], dst = ei[Eq + e];
        #pragma unroll
        for (int b = 0; b < Bq; b++) {
            atomicAdd(&agg[((size_t)(b*Sq + dst))*Hq + u],
                      ft[((size_t)(b*Sq + src))*Hq + u]);
        }
    }
}

// ------------------------------ head ----------------------------------------
__global__ __launch_bounds__(64)
void head_kernel(const float* __restrict__ ft, const float* __restrict__ agg,
                 const float* __restrict__ deg,
                 const float* __restrict__ gnn_W, const float* __restrict__ gnn_b,
                 const float* __restrict__ fc1_W, const float* __restrict__ fc1_b,
                 const float* __restrict__ ln1_g, const float* __restrict__ ln1_b,
                 const float* __restrict__ fc2_W, const float* __restrict__ fc2_b,
                 const float* __restrict__ ln2_g, const float* __restrict__ ln2_b,
                 const float* __restrict__ mlp_W1, const float* __restrict__ mlp_b1,
                 const float* __restrict__ mlp_W2, const float* __restrict__ mlp_b2,
                 float* __restrict__ out) {
    __shared__ __align__(16) float a_s[Hq];
    __shared__ __align__(16) float in_s[2*Hq];
    __shared__ __align__(16) float t_s[Hq];
    const int n = blockIdx.x;
    const int s = n % Sq;
    const int u = threadIdx.x;
    const float denom = fmaxf(deg[s], 1.0f);
    a_s[u]  = agg[(size_t)n*Hq + u] / denom;
    in_s[u] = ft[(size_t)n*Hq + u];
    __syncthreads();
    {
        float a0=0.f,a1=0.f,a2=0.f,a3=0.f;
        #pragma unroll
        for (int j = 0; j < Hq; j += 4) {
            a0 = fmaf(a_s[j+0], gnn_W[(j+0)*Hq + u], a0);
            a1 = fmaf(a_s[j+1], gnn_W[(j+1)*Hq + u], a1);
            a2 = fmaf(a_s[j+2], gnn_W[(j+2)*Hq + u], a2);
            a3 = fmaf(a_s[j+3], gnn_W[(j+3)*Hq + u], a3);
        }
        in_s[Hq+u] = ftanh(gnn_b[u] + ((a0+a1)+(a2+a3)));
    }
    __syncthreads();
    float v;
    {
        float a0=0.f,a1=0.f,a2=0.f,a3=0.f;
        #pragma unroll
        for (int j = 0; j < 2*Hq; j += 4) {
            a0 = fmaf(in_s[j+0], fc1_W[(j+0)*Hq + u], a0);
            a1 = fmaf(in_s[j+1], fc1_W[(j+1)*Hq + u], a1);
            a2 = fmaf(in_s[j+2], fc1_W[(j+2)*Hq + u], a2);
            a3 = fmaf(in_s[j+3], fc1_W[(j+3)*Hq + u], a3);
        }
        v = fc1_b[u] + ((a0+a1)+(a2+a3));
        float m = wave_sum64(v) * (1.0f/Hq);
        float d = v - m;
        float var = wave_sum64(d*d) * (1.0f/Hq);
        v = fmaxf(d * rsqrtf(var + 1e-5f) * ln1_g[u] + ln1_b[u], 0.0f);
    }
    t_s[u] = v;
    __syncthreads();
    {
        float a0=0.f,a1=0.f,a2=0.f,a3=0.f;
        #pragma unroll
        for (int j = 0; j < Hq; j += 4) {
            a0 = fmaf(t_s[j+0], fc2_W[(j+0)*Hq + u], a0);
            a1 = fmaf(t_s[j+1], fc2_W[(j+1)*Hq + u], a1);
            a2 = fmaf(t_s[j+2], fc2_W[(j+2)*Hq + u], a2);
            a3 = fmaf(t_s[j+3], fc2_W[(j+3)*Hq + u], a3);
        }
        v = fc2_b[u] + ((a0+a1)+(a2+a3));
        float m = wave_sum64(v) * (1.0f/Hq);
        float d = v - m;
        float var = wave_sum64(d*d) * (1.0f/Hq);
        v = fmaxf(d * rsqrtf(var + 1e-5f) * ln2_g[u] + ln2_b[u], 0.0f);
    }
    __syncthreads();
    a_s[u] = v;
    __syncthreads();
    {
        float a0=0.f,a1=0.f,a2=0.f,a3=0.f;
        #pragma unroll
        for (int j = 0; j < Hq; j += 4) {
            a0 = fmaf(a_s[j+0], mlp_W1[(j+0)*Hq + u], a0);
            a1 = fmaf(a_s[j+1], mlp_W1[(j+1)*Hq + u], a1);
            a2 = fmaf(a_s[j+2], mlp_W1[(j+2)*Hq + u], a2);
            a3 = fmaf(a_s[j+3], mlp_W1[(j+3)*Hq + u], a3);
        }
        v = fmaxf(mlp_b1[u] + ((a0+a1)+(a2+a3)), 0.0f);
    }
    float p = wave_sum64(v * mlp_W2[u]);
    if (u == 0) out[n] = p + mlp_b2[0];
}

extern "C" void kernel_launch(void* const* d_in, const int* in_sizes, int n_in,
                              void* d_out, int out_size, void* d_ws, size_t ws_size,
                              hipStream_t stream) {
    (void)in_sizes; (void)n_in; (void)out_size; (void)ws_size;
    const float* price  = (const float*)d_in[0];
    const float* tweets = (const float*)d_in[1];
    const int*   counts = (const int*)d_in[2];
    const int*   ei     = (const int*)d_in[3];
    const float* pg_Wi = (const float*)d_in[5];
    const float* pg_Wh = (const float*)d_in[6];
    const float* pg_bi = (const float*)d_in[7];
    const float* pg_bh = (const float*)d_in[8];
    const float* tg_Wi = (const float*)d_in[9];
    const float* tg_Wh = (const float*)d_in[10];
    const float* tg_bi = (const float*)d_in[11];
    const float* tg_bh = (const float*)d_in[12];
    const float* dg_Wi = (const float*)d_in[13];
    const float* dg_Wh = (const float*)d_in[14];
    const float* dg_bi = (const float*)d_in[15];
    const float* dg_bh = (const float*)d_in[16];
    const float* bil_A = (const float*)d_in[17];
    const float* bil_b = (const float*)d_in[18];
    const float* gnn_W = (const float*)d_in[19];
    const float* gnn_b = (const float*)d_in[20];
    const float* fc1_W = (const float*)d_in[21];
    const float* fc1_b = (const float*)d_in[22];
    const float* ln1_g = (const float*)d_in[23];
    const float* ln1_b = (const float*)d_in[24];
    const float* fc2_W = (const float*)d_in[25];
    const float* fc2_b = (const float*)d_in[26];
    const float* ln2_g = (const float*)d_in[27];
    const float* ln2_b = (const float*)d_in[28];
    const float* mlp_W1 = (const float*)d_in[29];
    const float* mlp_b1 = (const float*)d_in[30];
    const float* mlp_W2 = (const float*)d_in[31];
    const float* mlp_b2 = (const float*)d_in[32];

    float* ws      = (float*)d_ws;
    float* x_price = ws;                   // 4000*64   = 256000
    float* news    = ws + 256000;          // 20000*64  = 1280000
    float* text    = ws + 1536000;         // 4000*64
    float* ft      = ws + 1792000;         // 4000*64
    float* agg     = ws + 2048000;         // 8*500*64  = 256000
    float* deg     = ws + 2304000;         // 512
    short* Wf_hi   = (short*)(ws + 2304512);           // 98304 shorts
    short* Wf_lo   = Wf_hi  + 98304;
    short* Whp_hi  = Wf_lo  + 98304;                   // 2*12*64*8 = 12288
    short* Whp_lo  = Whp_hi + 12288;
    short* Bf_hi   = Whp_lo + 12288;                   // 512*64*8 = 262144
    short* Bf_lo   = Bf_hi  + 262144;

    hipMemsetAsync(agg, 0, (256000 + 512)*sizeof(float), stream);

    wfrag_prep_kernel<<<NKT*NNT, 64, 0, stream>>>(tg_Wi, Wf_hi, Wf_lo);
    wfrag_prep_kernel<<<2*NNT, 64, 0, stream>>>(pg_Wh, Whp_hi, Whp_lo);
    bilfrag_prep_kernel<<<128*4, 64, 0, stream>>>(bil_A, Bf_hi, Bf_lo);

    price_gru_mfma_kernel<<<NS/PSEQ, 256, 0, stream>>>(price, pg_Wi, Whp_hi, Whp_lo,
                                                       pg_bi, pg_bh, x_price);
    tweet_gru_kernel<<<NTt/TG, 256, 0, stream>>>(tweets, counts, Wf_hi, Wf_lo,
                                                 tg_Wh, tg_bi, tg_bh, news);
    date_gru_kernel<<<NS, 192, 0, stream>>>(news, dg_Wi, dg_Wh, dg_bi, dg_bh, text);
    bilinear_mfma_kernel<<<NS/16, 256, 0, stream>>>(text, x_price, Bf_hi, Bf_lo, bil_b, ft);
    deg_kernel<<<(Eq+255)/256, 256, 0, stream>>>(ei, deg);
    agg_kernel<<<(Eq*Hq)/256, 256, 0, stream>>>(ei, ft, agg);
    head_kernel<<<NS, 64, 0, stream>>>(ft, agg, deg,
                                       gnn_W, gnn_b, fc1_W, fc1_b, ln1_g, ln1_b,
                                       fc2_W, fc2_b, ln2_g, ln2_b,
                                       mlp_W1, mlp_b1, mlp_W2, mlp_b2,
                                       (float*)d_out);
}

// Round 3
// 854.143 us; speedup vs baseline: 1.1066x; 1.0297x over previous
//
#include <hip/hip_runtime.h>
#include <math.h>

#define Bq 8
#define Sq 500
#define Tq 30
#define Dq 5
#define Kq 10
#define Hq 64
#define TWq 512
#define Eq 8000
#define NS (Bq*Sq)      // 4000
#define NTt (NS*Dq)     // 20000
#define G3 (3*Hq)       // 192
#define TG 4            // tweet seqs per block

#define MR 48           // padded GEMM rows (TG*Kq=40 -> 48)
#define KC 64           // K chunk staged per iteration
#define XPITCH 72       // LDS row pitch in bf16 elems (144B: 2-way bank alias = free)
#define XGP 196         // xg fp32 pitch (196%32=4 -> conflict-free epilogue)
#define NKT (TWq/32)    // 16 k-tiles of 32
#define NNT (G3/16)     // 12 n-tiles of 16
#define PSEQ 16         // price seqs per block

#define XROWS 40        // rows of xg actually used (TG*Kq)
#define STG_PLANE (MR*XPITCH)        // 3456 shorts per hi/lo plane
#define STG_BUF  (2*STG_PLANE)       // 6912 shorts per buffer (hi+lo)

typedef __attribute__((ext_vector_type(8))) short short8_t;
typedef __attribute__((ext_vector_type(4))) float float4_t;

__device__ __forceinline__ float fsig(float x) {
    return 1.0f / (1.0f + __expf(-x));
}
__device__ __forceinline__ float ftanh(float x) {
    // 1 - 2/(e^{2x}+1); exact limits at +-inf
    return 1.0f - 2.0f / (__expf(2.0f * x) + 1.0f);
}

__device__ __forceinline__ float wave_sum64(float v) {
    #pragma unroll
    for (int off = 32; off; off >>= 1) v += __shfl_xor(v, off, 64);
    return v;
}

__device__ __forceinline__ short f32_to_bf16_rn(float f) {
    union { float f; unsigned u; } v; v.f = f;
    unsigned r = v.u + 0x7fffu + ((v.u >> 16) & 1u);
    return (short)(r >> 16);
}
__device__ __forceinline__ float bf16_to_f32(short s) {
    union { unsigned u; float f; } v; v.u = ((unsigned)(unsigned short)s) << 16;
    return v.f;
}

// ---- prep: [K x 192] row-major -> MFMA B-frag order, split hi/lo bf16 ------
// Wf[kt][nt][lane][j] = W[kt*32 + (lane>>4)*8 + j][nt*16 + (lane&15)]
// grid = (K/32)*NNT blocks of 64
__global__ __launch_bounds__(64)
void wfrag_prep_kernel(const float* __restrict__ Wi,
                       short* __restrict__ Wf_hi, short* __restrict__ Wf_lo) {
    const int kt = blockIdx.x / NNT;
    const int nt = blockIdx.x - kt*NNT;
    const int lane = threadIdx.x;
    const int quad = lane >> 4, l16 = lane & 15;
    short h[8], l[8];
    #pragma unroll
    for (int j = 0; j < 8; j++) {
        int k = kt*32 + quad*8 + j;
        int n = nt*16 + l16;
        float w = Wi[(size_t)k*G3 + n];
        short hi = f32_to_bf16_rn(w);
        short lo = f32_to_bf16_rn(w - bf16_to_f32(hi));
        h[j] = hi; l[j] = lo;
    }
    size_t off = ((size_t)blockIdx.x*64 + lane)*8;
    *(short8_t*)(Wf_hi + off) = *(const short8_t*)h;
    *(short8_t*)(Wf_lo + off) = *(const short8_t*)l;
}

// ---- prep for bil_A: B[kidx][n] = bil_A[n*4096 + kidx]; grid 128*4 ---------
__global__ __launch_bounds__(64)
void bilfrag_prep_kernel(const float* __restrict__ A,
                         short* __restrict__ Bf_hi, short* __restrict__ Bf_lo) {
    const int kt = blockIdx.x >> 2;        // 0..127
    const int nt = blockIdx.x & 3;         // 0..3
    const int lane = threadIdx.x;
    const int quad = lane >> 4, l16 = lane & 15;
    short h[8], l[8];
    #pragma unroll
    for (int j = 0; j < 8; j++) {
        int kidx = kt*32 + quad*8 + j;
        int n = nt*16 + l16;
        float w = A[(size_t)n*4096 + kidx];
        short hi = f32_to_bf16_rn(w);
        h[j] = hi; l[j] = f32_to_bf16_rn(w - bf16_to_f32(hi));
    }
    size_t off = ((size_t)blockIdx.x*64 + lane)*8;
    *(short8_t*)(Bf_hi + off) = *(const short8_t*)h;
    *(short8_t*)(Bf_lo + off) = *(const short8_t*)l;
}

// -------- price GRU via MFMA: 16 seqs/block, gate-aligned n-tiles -----------
// wave w owns output units u = 16w + (lane&15); gates r/z/n come from
// n-tiles {w, 4+w, 8+w} so r,z,n land in the SAME lane -> no hg LDS trip.
__global__ __launch_bounds__(256)
void price_gru_mfma_kernel(const float* __restrict__ price,
                           const float* __restrict__ Wi,
                           const short* __restrict__ Whf_hi, const short* __restrict__ Whf_lo,
                           const float* __restrict__ bi, const float* __restrict__ bh,
                           float* __restrict__ xout) {
    __shared__ __align__(16) float price_s[PSEQ*90];
    __shared__ __align__(16) short h_hi[PSEQ*72];
    __shared__ __align__(16) short h_lo[PSEQ*72];
    const int tid = threadIdx.x;
    const int n0 = blockIdx.x * PSEQ;
    const int wv = tid >> 6;
    const int lane = tid & 63;
    const int quad = lane >> 4;
    const int l16 = lane & 15;
    const int u = wv*16 + l16;
    for (int i = tid; i < PSEQ*90; i += 256) price_s[i] = price[(size_t)n0*90 + i];
    for (int i = tid; i < PSEQ*72; i += 256) { h_hi[i] = 0; h_lo[i] = 0; }
    float wir[3], wiz[3], win[3];
    #pragma unroll
    for (int k = 0; k < 3; k++) {
        wir[k] = Wi[k*G3 + u];
        wiz[k] = Wi[k*G3 + 64 + u];
        win[k] = Wi[k*G3 + 128 + u];
    }
    const float cbr = bi[u] + bh[u];
    const float cbz = bi[64+u] + bh[64+u];
    const float bin = bi[128+u];
    const float bhn = bh[128+u];
    short8_t bfh[2][3], bfl[2][3];
    #pragma unroll
    for (int kt = 0; kt < 2; kt++)
        #pragma unroll
        for (int g = 0; g < 3; g++) {
            size_t off = (((size_t)kt*NNT + (g*4 + wv))*64 + lane)*8;
            bfh[kt][g] = *(const short8_t*)(Whf_hi + off);
            bfl[kt][g] = *(const short8_t*)(Whf_lo + off);
        }
    float hprev[4] = {0.f,0.f,0.f,0.f}, sum[4] = {0.f,0.f,0.f,0.f};
    __syncthreads();
    for (int t = 0; t < Tq; t++) {
        short8_t ah[2], al[2];
        #pragma unroll
        for (int kt = 0; kt < 2; kt++) {
            int addr = l16*72 + kt*32 + quad*8;
            ah[kt] = *(const short8_t*)&h_hi[addr];
            al[kt] = *(const short8_t*)&h_lo[addr];
        }
        float4_t accr = {0.f,0.f,0.f,0.f}, accz = {0.f,0.f,0.f,0.f}, accn = {0.f,0.f,0.f,0.f};
        #pragma unroll
        for (int kt = 0; kt < 2; kt++) {
            accr = __builtin_amdgcn_mfma_f32_16x16x32_bf16(ah[kt], bfh[kt][0], accr, 0,0,0);
            accr = __builtin_amdgcn_mfma_f32_16x16x32_bf16(ah[kt], bfl[kt][0], accr, 0,0,0);
            accr = __builtin_amdgcn_mfma_f32_16x16x32_bf16(al[kt], bfh[kt][0], accr, 0,0,0);
            accz = __builtin_amdgcn_mfma_f32_16x16x32_bf16(ah[kt], bfh[kt][1], accz, 0,0,0);
            accz = __builtin_amdgcn_mfma_f32_16x16x32_bf16(ah[kt], bfl[kt][1], accz, 0,0,0);
            accz = __builtin_amdgcn_mfma_f32_16x16x32_bf16(al[kt], bfh[kt][1], accz, 0,0,0);
            accn = __builtin_amdgcn_mfma_f32_16x16x32_bf16(ah[kt], bfh[kt][2], accn, 0,0,0);
            accn = __builtin_amdgcn_mfma_f32_16x16x32_bf16(ah[kt], bfl[kt][2], accn, 0,0,0);
            accn = __builtin_amdgcn_mfma_f32_16x16x32_bf16(al[kt], bfl[kt][2], accn, 0,0,0);
        }
        __syncthreads();   // A-frag reads done before h is rewritten
        #pragma unroll
        for (int r = 0; r < 4; r++) {
            const int s = quad*4 + r;
            float p0 = price_s[s*90 + t*3 + 0];
            float p1 = price_s[s*90 + t*3 + 1];
            float p2 = price_s[s*90 + t*3 + 2];
            float xr = fmaf(p2, wir[2], fmaf(p1, wir[1], fmaf(p0, wir[0], cbr)));
            float xz = fmaf(p2, wiz[2], fmaf(p1, wiz[1], fmaf(p0, wiz[0], cbz)));
            float xn = fmaf(p2, win[2], fmaf(p1, win[1], fmaf(p0, win[0], bin)));
            float rg = fsig(xr + accr[r]);
            float zg = fsig(xz + accz[r]);
            float ng = ftanh(xn + rg*(accn[r] + bhn));
            float h = (1.0f - zg)*ng + zg*hprev[r];
            hprev[r] = h; sum[r] += h;
            short hh = f32_to_bf16_rn(h);
            h_hi[s*72 + u] = hh;
            h_lo[s*72 + u] = f32_to_bf16_rn(h - bf16_to_f32(hh));
        }
        __syncthreads();   // h writes visible before next A-frag read
    }
    #pragma unroll
    for (int r = 0; r < 4; r++)
        xout[(size_t)(n0 + quad*4 + r)*Hq + u] = sum[r];
}

// ------------- tweet GRU: MFMA split-bf16 projection + MFMA recurrence ------
// v3 = round-1 structure + gate-aligned MFMA recurrence (price-kernel style):
// A rows = seqs (16-row tile, 4 live); wave w owns units u=16w+l16 via
// n-tiles {w, 4+w, 8+w} so r/z/n land in the same lane.
__global__ __launch_bounds__(256, 4)
void tweet_gru_kernel(const float* __restrict__ tweets,
                      const int* __restrict__ counts,
                      const short* __restrict__ Wf_hi, const short* __restrict__ Wf_lo,
                      const short* __restrict__ Wht_hi, const short* __restrict__ Wht_lo,
                      const float* __restrict__ bi, const float* __restrict__ bh,
                      float* __restrict__ news) {
    __shared__ __align__(16) char smem[XROWS*XGP*4];   // 31360 B
    __shared__ __align__(16) short rh_hi[16*72];       // recurrence h A-rows
    __shared__ __align__(16) short rh_lo[16*72];
    __shared__ int len_s[TG];
    __shared__ int tmax_s;
    short* stg = (short*)smem;     // [2 bufs][hi 3456 | lo 3456] shorts = 27648 B
    float* xg  = (float*)smem;     // [XROWS][XGP] f32, aliases staging

    const int tid  = threadIdx.x;
    const int n0   = blockIdx.x * TG;
    const int wave = tid >> 6;
    const int lane = tid & 63;
    const int quad = lane >> 4;
    const int l16  = lane & 15;

    if (tid < TG) {
        int c = counts[n0 + tid];
        len_s[tid] = c < 0 ? 0 : (c > Kq ? Kq : c);
    }
    for (int i = tid; i < 16*72; i += 256) { rh_hi[i] = 0; rh_lo[i] = 0; }
    __syncthreads();
    if (tid == 0) {
        int m01 = len_s[0] > len_s[1] ? len_s[0] : len_s[1];
        int m23 = len_s[2] > len_s[3] ? len_s[2] : len_s[3];
        tmax_s = m01 > m23 ? m01 : m23;
    }

    // ---- hoisted staging descriptors (640 float4 items, stride 256) --------
    const float* gp[3];
    int lofs[3];
    bool val[3];
    #pragma unroll
    for (int j = 0; j < 3; j++) {
        const int ii = tid + j*256;
        const bool ok = ii < TG*Kq*(KC/4);        // < 640
        const int i = ok ? ii : 0;
        const int row = i >> 4;
        const int c4  = i & 15;
        const int s   = (row*205) >> 11;          // row/10 for row<48
        const int t   = row - s*10;
        val[j]  = ok && (t < len_s[s]);
        gp[j]   = tweets + (((size_t)(n0+s))*Kq + t)*TWq + c4*4;
        lofs[j] = row*XPITCH + c4*4;
    }

    float4_t acc[3][3];   // [mt][ntl]
    #pragma unroll
    for (int a = 0; a < 3; a++)
        #pragma unroll
        for (int b = 0; b < 3; b++)
            acc[a][b] = (float4_t){0.f, 0.f, 0.f, 0.f};

    // ---- prologue: stage chunk 0 into buffer 0 ----
    #pragma unroll
    for (int j = 0; j < 3; j++) if (val[j]) {
        float4 v = *(const float4*)(gp[j]);
        float f[4] = {v.x, v.y, v.z, v.w};
        short hh[4], ll[4];
        #pragma unroll
        for (int q = 0; q < 4; q++) {
            short hi = f32_to_bf16_rn(f[q]);
            hh[q] = hi;
            ll[q] = f32_to_bf16_rn(f[q] - bf16_to_f32(hi));
        }
        *(short4*)&stg[lofs[j]]             = *(const short4*)hh;
        *(short4*)&stg[STG_PLANE + lofs[j]] = *(const short4*)ll;
    }
    __syncthreads();

    for (int ch = 0; ch < TWq/KC; ch++) {
        const int cur = ch & 1;
        // (1) issue next chunk's global loads early
        float4 v[3];
        if (ch < TWq/KC - 1) {
            #pragma unroll
            for (int j = 0; j < 3; j++) if (val[j])
                v[j] = *(const float4*)(gp[j] + (ch+1)*KC);
        }
        // (2) MFMA on current buffer
        const short* xh = stg + cur*STG_BUF;
        const short* xl = xh + STG_PLANE;
        #pragma unroll
        for (int ks = 0; ks < KC/32; ks++) {
            const int kt = ch*(KC/32) + ks;
            short8_t bh_[3], bl_[3];
            #pragma unroll
            for (int ntl = 0; ntl < 3; ntl++) {
                size_t off = (((size_t)kt*NNT + (wave*3 + ntl))*64 + lane)*8;
                bh_[ntl] = *(const short8_t*)(Wf_hi + off);
                bl_[ntl] = *(const short8_t*)(Wf_lo + off);
            }
            short8_t ah_[3], al_[3];
            #pragma unroll
            for (int mt = 0; mt < 3; mt++) {
                int addr = (mt*16 + l16)*XPITCH + ks*32 + quad*8;
                ah_[mt] = *(const short8_t*)&xh[addr];
                al_[mt] = *(const short8_t*)&xl[addr];
            }
            #pragma unroll
            for (int mt = 0; mt < 3; mt++)
                #pragma unroll
                for (int ntl = 0; ntl < 3; ntl++) {
                    acc[mt][ntl] = __builtin_amdgcn_mfma_f32_16x16x32_bf16(ah_[mt], bh_[ntl], acc[mt][ntl], 0, 0, 0);
                    acc[mt][ntl] = __builtin_amdgcn_mfma_f32_16x16x32_bf16(ah_[mt], bl_[ntl], acc[mt][ntl], 0, 0, 0);
                    acc[mt][ntl] = __builtin_amdgcn_mfma_f32_16x16x32_bf16(al_[mt], bh_[ntl], acc[mt][ntl], 0, 0, 0);
                }
        }
        // (3) convert + write next chunk into the other buffer
        if (ch < TWq/KC - 1) {
            short* yh = stg + (cur^1)*STG_BUF;
            short* yl = yh + STG_PLANE;
            #pragma unroll
            for (int j = 0; j < 3; j++) if (val[j]) {
                float f[4] = {v[j].x, v[j].y, v[j].z, v[j].w};
                short hh[4], ll[4];
                #pragma unroll
                for (int q = 0; q < 4; q++) {
                    short hi = f32_to_bf16_rn(f[q]);
                    hh[q] = hi;
                    ll[q] = f32_to_bf16_rn(f[q] - bf16_to_f32(hi));
                }
                *(short4*)&yh[lofs[j]] = *(const short4*)hh;
                *(short4*)&yl[lofs[j]] = *(const short4*)ll;
            }
        }
        __syncthreads();   // next buffer ready; current buffer reads done
    }

    // ---- epilogue: acc -> xg (only the 40 live rows) ----
    #pragma unroll
    for (int ntl = 0; ntl < 3; ntl++) {
        const int col = (wave*3 + ntl)*16 + l16;
        const float bic = bi[col];
        #pragma unroll
        for (int mt = 0; mt < 3; mt++) {
            const int row0 = mt*16 + quad*4;
            if (row0 < XROWS) {
                #pragma unroll
                for (int r2 = 0; r2 < 4; r2++)
                    xg[(row0 + r2)*XGP + col] = acc[mt][ntl][r2] + bic;
            }
        }
    }

    // ---- recurrence via MFMA (gate-aligned) ----
    const int u = wave*16 + l16;
    short8_t tbh[2][3], tbl[2][3];
    #pragma unroll
    for (int kt = 0; kt < 2; kt++)
        #pragma unroll
        for (int g = 0; g < 3; g++) {
            size_t off = (((size_t)kt*NNT + (g*4 + wave))*64 + lane)*8;
            tbh[kt][g] = *(const short8_t*)(Wht_hi + off);
            tbl[kt][g] = *(const short8_t*)(Wht_lo + off);
        }
    const float bhr = bh[u];
    const float bhz = bh[64+u];
    const float bhn = bh[128+u];
    int lp[4];
    #pragma unroll
    for (int r = 0; r < 4; r++) lp[r] = len_s[r];
    float hprev[4] = {0.f,0.f,0.f,0.f}, sum[4] = {0.f,0.f,0.f,0.f};
    const int tmax = tmax_s;
    for (int t = 0; t < tmax; t++) {
        const int ha = l16*72;
        short8_t ah0 = *(const short8_t*)&rh_hi[ha + quad*8];
        short8_t ah1 = *(const short8_t*)&rh_hi[ha + 32 + quad*8];
        short8_t al0 = *(const short8_t*)&rh_lo[ha + quad*8];
        short8_t al1 = *(const short8_t*)&rh_lo[ha + 32 + quad*8];
        float4_t ar = {0.f,0.f,0.f,0.f}, az = {0.f,0.f,0.f,0.f}, an = {0.f,0.f,0.f,0.f};
        ar = __builtin_amdgcn_mfma_f32_16x16x32_bf16(ah0, tbh[0][0], ar, 0,0,0);
        ar = __builtin_amdgcn_mfma_f32_16x16x32_bf16(ah0, tbl[0][0], ar, 0,0,0);
        ar = __builtin_amdgcn_mfma_f32_16x16x32_bf16(al0, tbh[0][0], ar, 0,0,0);
        ar = __builtin_amdgcn_mfma_f32_16x16x32_bf16(ah1, tbh[1][0], ar, 0,0,0);
        ar = __builtin_amdgcn_mfma_f32_16x16x32_bf16(ah1, tbl[1][0], ar, 0,0,0);
        ar = __builtin_amdgcn_mfma_f32_16x16x32_bf16(al1, tbh[1][0], ar, 0,0,0);
        az = __builtin_amdgcn_mfma_f32_16x16x32_bf16(ah0, tbh[0][1], az, 0,0,0);
        az = __builtin_amdgcn_mfma_f32_16x16x32_bf16(ah0, tbl[0][1], az, 0,0,0);
        az = __builtin_amdgcn_mfma_f32_16x16x32_bf16(al0, tbh[0][1], az, 0,0,0);
        az = __builtin_amdgcn_mfma_f32_16x16x32_bf16(ah1, tbh[1][1], az, 0,0,0);
        az = __builtin_amdgcn_mfma_f32_16x16x32_bf16(ah1, tbl[1][1], az, 0,0,0);
        az = __builtin_amdgcn_mfma_f32_16x16x32_bf16(al1, tbh[1][1], az, 0,0,0);
        an = __builtin_amdgcn_mfma_f32_16x16x32_bf16(ah0, tbh[0][2], an, 0,0,0);
        an = __builtin_amdgcn_mfma_f32_16x16x32_bf16(ah0, tbl[0][2], an, 0,0,0);
        an = __builtin_amdgcn_mfma_f32_16x16x32_bf16(al0, tbh[0][2], an, 0,0,0);
        an = __builtin_amdgcn_mfma_f32_16x16x32_bf16(ah1, tbh[1][2], an, 0,0,0);
        an = __builtin_amdgcn_mfma_f32_16x16x32_bf16(ah1, tbl[1][2], an, 0,0,0);
        an = __builtin_amdgcn_mfma_f32_16x16x32_bf16(al1, tbh[1][2], an, 0,0,0);
        __syncthreads();   // A-frag reads (and epilogue xg writes at t=0) done
        if (quad == 0) {
            #pragma unroll
            for (int r = 0; r < 4; r++) {
                if (t < lp[r]) {
                    const float* xr = &xg[(r*Kq + t)*XGP];
                    float rg = fsig(xr[u]        + ar[r] + bhr);
                    float zg = fsig(xr[Hq+u]     + az[r] + bhz);
                    float ng = ftanh(xr[2*Hq+u]  + rg*(an[r] + bhn));
                    float hn = (1.0f - zg)*ng + zg*hprev[r];
                    hprev[r] = hn; sum[r] += hn;
                    short hh = f32_to_bf16_rn(hn);
                    rh_hi[r*72 + u] = hh;
                    rh_lo[r*72 + u] = f32_to_bf16_rn(hn - bf16_to_f32(hh));
                }
            }
        }
        __syncthreads();   // h writes visible before next A-frag read
    }
    if (quad == 0) {
        #pragma unroll
        for (int r = 0; r < 4; r++)
            news[(size_t)(n0 + r)*Hq + u] = sum[r];
    }
}

// ---------------- date GRU: one block (192 thr) per sequence ----------------
__global__ __launch_bounds__(192)
void date_gru_kernel(const float* __restrict__ news,
                     const float* __restrict__ Wi, const float* __restrict__ Wh,
                     const float* __restrict__ bi, const float* __restrict__ bh,
                     float* __restrict__ text) {
    __shared__ __align__(16) float nw_s[Dq*Hq];
    __shared__ __align__(16) float h_s[Hq];
    __shared__ __align__(16) float xg_s[G3];
    __shared__ __align__(16) float hg_s[G3];
    const int n = blockIdx.x;
    const int g = threadIdx.x;
    for (int i = g; i < Dq*Hq; i += 192) nw_s[i] = news[(size_t)n*Dq*Hq + i];
    float wi[Hq], wh[Hq];
    #pragma unroll
    for (int j = 0; j < Hq; j++) { wi[j] = Wi[j*G3+g]; wh[j] = Wh[j*G3+g]; }
    const float big = bi[g], bhg = bh[g];
    if (g < Hq) h_s[g] = 0.0f;
    float hreg = 0.0f, sum = 0.0f;
    __syncthreads();
    for (int t = 0; t < Dq; t++) {
        float a0=0.f,a1=0.f,a2=0.f,a3=0.f, b0=0.f,b1=0.f,b2=0.f,b3=0.f;
        #pragma unroll
        for (int j = 0; j < Hq; j += 4) {
            float4 nv = *(const float4*)&nw_s[t*Hq + j];
            float4 hv = *(const float4*)&h_s[j];
            a0 = fmaf(nv.x, wi[j+0], a0);
            a1 = fmaf(nv.y, wi[j+1], a1);
            a2 = fmaf(nv.z, wi[j+2], a2);
            a3 = fmaf(nv.w, wi[j+3], a3);
            b0 = fmaf(hv.x, wh[j+0], b0);
            b1 = fmaf(hv.y, wh[j+1], b1);
            b2 = fmaf(hv.z, wh[j+2], b2);
            b3 = fmaf(hv.w, wh[j+3], b3);
        }
        xg_s[g] = big + ((a0+a1)+(a2+a3));
        hg_s[g] = bhg + ((b0+b1)+(b2+b3));
        __syncthreads();
        if (g < Hq) {
            float r  = fsig(xg_s[g]      + hg_s[g]);
            float z  = fsig(xg_s[Hq+g]   + hg_s[Hq+g]);
            float nn = ftanh(xg_s[2*Hq+g] + r*hg_s[2*Hq+g]);
            hreg = (1.0f - z)*nn + z*hreg;
            sum += hreg;
            h_s[g] = hreg;
        }
        __syncthreads();
    }
    if (g < Hq) text[(size_t)n*Hq + g] = sum;
}

// -------- bilinear via MFMA: C[n,k] = tanh(sum_ij P[n,ij] A2[k,ij] + b_k) ---
#define TP 68
#define XP 72
__global__ __launch_bounds__(256)
void bilinear_mfma_kernel(const float* __restrict__ text, const float* __restrict__ x,
                          const short* __restrict__ Bf_hi, const short* __restrict__ Bf_lo,
                          const float* __restrict__ bb, float* __restrict__ ft) {
    __shared__ __align__(16) float t_s[16*TP];
    __shared__ __align__(16) float x_s[16*XP];
    const int tid = threadIdx.x;
    const int n0 = blockIdx.x * 16;
    const int wv = tid >> 6, lane = tid & 63, quad = lane >> 4, l16 = lane & 15;
    for (int i = tid; i < 16*64; i += 256) {
        int r = i >> 6, c = i & 63;
        t_s[r*TP + c] = text[(size_t)(n0 + r)*Hq + c];
        x_s[r*XP + c] = x[(size_t)(n0 + r)*Hq + c];
    }
    float4_t acc = {0.f,0.f,0.f,0.f};
    __syncthreads();
    for (int kt = 0; kt < 128; kt++) {
        const int i  = kt >> 1;
        const int j0 = (kt & 1)*32 + quad*8;
        size_t boff = (((size_t)kt*4 + wv)*64 + lane)*8;
        short8_t bh_ = *(const short8_t*)(Bf_hi + boff);
        short8_t bl_ = *(const short8_t*)(Bf_lo + boff);
        float ti = t_s[l16*TP + i];
        float xv[8];
        *(float4*)&xv[0] = *(const float4*)&x_s[l16*XP + j0];
        *(float4*)&xv[4] = *(const float4*)&x_s[l16*XP + j0 + 4];
        short ph[8], pl[8];
        #pragma unroll
        for (int jj = 0; jj < 8; jj++) {
            float p = ti * xv[jj];
            short hi = f32_to_bf16_rn(p);
            ph[jj] = hi;
            pl[jj] = f32_to_bf16_rn(p - bf16_to_f32(hi));
        }
        short8_t ah = *(const short8_t*)ph;
        short8_t al = *(const short8_t*)pl;
        acc = __builtin_amdgcn_mfma_f32_16x16x32_bf16(ah, bh_, acc, 0,0,0);
        acc = __builtin_amdgcn_mfma_f32_16x16x32_bf16(ah, bl_, acc, 0,0,0);
        acc = __builtin_amdgcn_mfma_f32_16x16x32_bf16(al, bh_, acc, 0,0,0);
    }
    const int col = wv*16 + l16;
    const float bk = bb[col];
    #pragma unroll
    for (int r = 0; r < 4; r++) {
        int n = quad*4 + r;
        ft[(size_t)(n0 + n)*Hq + col] = ftanh(acc[r] + bk);
    }
}

// ----------------------------- GNN ------------------------------------------
__global__ void deg_kernel(const int* __restrict__ ei, float* __restrict__ deg) {
    int e = blockIdx.x*256 + threadIdx.x;
    if (e < Eq) atomicAdd(&deg[ei[Eq + e]], 1.0f);
}

__global__ void agg_kernel(const int* __restrict__ ei, const float* __restrict__ ft,
                           float* __restrict__ agg) {
    int gid = blockIdx.x*256 + threadIdx.x;
    int e = gid >> 6;
    int u = gid & 63;
    if (e < Eq) {
        int src = ei[e], dst = ei[Eq + e];
        #pragma unroll
        for (int b = 0; b < Bq; b++) {
            atomicAdd(&agg[((size_t)(b*Sq + dst))*Hq + u],
                      ft[((size_t)(b*Sq + src))*Hq + u]);
        }
    }
}

// ------------------------------ head ----------------------------------------
__global__ __launch_bounds__(64)
void head_kernel(const float* __restrict__ ft, const float* __restrict__ agg,
                 const float* __restrict__ deg,
                 const float* __restrict__ gnn_W, const float* __restrict__ gnn_b,
                 const float* __restrict__ fc1_W, const float* __restrict__ fc1_b,
                 const float* __restrict__ ln1_g, const float* __restrict__ ln1_b,
                 const float* __restrict__ fc2_W, const float* __restrict__ fc2_b,
                 const float* __restrict__ ln2_g, const float* __restrict__ ln2_b,
                 const float* __restrict__ mlp_W1, const float* __restrict__ mlp_b1,
                 const float* __restrict__ mlp_W2, const float* __restrict__ mlp_b2,
                 float* __restrict__ out) {
    __shared__ __align__(16) float a_s[Hq];
    __shared__ __align__(16) float in_s[2*Hq];
    __shared__ __align__(16) float t_s[Hq];
    const int n = blockIdx.x;
    const int s = n % Sq;
    const int u = threadIdx.x;
    const float denom = fmaxf(deg[s], 1.0f);
    a_s[u]  = agg[(size_t)n*Hq + u] / denom;
    in_s[u] = ft[(size_t)n*Hq + u];
    __syncthreads();
    {
        float a0=0.f,a1=0.f,a2=0.f,a3=0.f;
        #pragma unroll
        for (int j = 0; j < Hq; j += 4) {
            a0 = fmaf(a_s[j+0], gnn_W[(j+0)*Hq + u], a0);
            a1 = fmaf(a_s[j+1], gnn_W[(j+1)*Hq + u], a1);
            a2 = fmaf(a_s[j+2], gnn_W[(j+2)*Hq + u], a2);
            a3 = fmaf(a_s[j+3], gnn_W[(j+3)*Hq + u], a3);
        }
        in_s[Hq+u] = ftanh(gnn_b[u] + ((a0+a1)+(a2+a3)));
    }
    __syncthreads();
    float v;
    {
        float a0=0.f,a1=0.f,a2=0.f,a3=0.f;
        #pragma unroll
        for (int j = 0; j < 2*Hq; j += 4) {
            a0 = fmaf(in_s[j+0], fc1_W[(j+0)*Hq + u], a0);
            a1 = fmaf(in_s[j+1], fc1_W[(j+1)*Hq + u], a1);
            a2 = fmaf(in_s[j+2], fc1_W[(j+2)*Hq + u], a2);
            a3 = fmaf(in_s[j+3], fc1_W[(j+3)*Hq + u], a3);
        }
        v = fc1_b[u] + ((a0+a1)+(a2+a3));
        float m = wave_sum64(v) * (1.0f/Hq);
        float d = v - m;
        float var = wave_sum64(d*d) * (1.0f/Hq);
        v = fmaxf(d * rsqrtf(var + 1e-5f) * ln1_g[u] + ln1_b[u], 0.0f);
    }
    t_s[u] = v;
    __syncthreads();
    {
        float a0=0.f,a1=0.f,a2=0.f,a3=0.f;
        #pragma unroll
        for (int j = 0; j < Hq; j += 4) {
            a0 = fmaf(t_s[j+0], fc2_W[(j+0)*Hq + u], a0);
            a1 = fmaf(t_s[j+1], fc2_W[(j+1)*Hq + u], a1);
            a2 = fmaf(t_s[j+2], fc2_W[(j+2)*Hq + u], a2);
            a3 = fmaf(t_s[j+3], fc2_W[(j+3)*Hq + u], a3);
        }
        v = fc2_b[u] + ((a0+a1)+(a2+a3));
        float m = wave_sum64(v) * (1.0f/Hq);
        float d = v - m;
        float var = wave_sum64(d*d) * (1.0f/Hq);
        v = fmaxf(d * rsqrtf(var + 1e-5f) * ln2_g[u] + ln2_b[u], 0.0f);
    }
    __syncthreads();
    a_s[u] = v;
    __syncthreads();
    {
        float a0=0.f,a1=0.f,a2=0.f,a3=0.f;
        #pragma unroll
        for (int j = 0; j < Hq; j += 4) {
            a0 = fmaf(a_s[j+0], mlp_W1[(j+0)*Hq + u], a0);
            a1 = fmaf(a_s[j+1], mlp_W1[(j+1)*Hq + u], a1);
            a2 = fmaf(a_s[j+2], mlp_W1[(j+2)*Hq + u], a2);
            a3 = fmaf(a_s[j+3], mlp_W1[(j+3)*Hq + u], a3);
        }
        v = fmaxf(mlp_b1[u] + ((a0+a1)+(a2+a3)), 0.0f);
    }
    float p = wave_sum64(v * mlp_W2[u]);
    if (u == 0) out[n] = p + mlp_b2[0];
}

extern "C" void kernel_launch(void* const* d_in, const int* in_sizes, int n_in,
                              void* d_out, int out_size, void* d_ws, size_t ws_size,
                              hipStream_t stream) {
    (void)in_sizes; (void)n_in; (void)out_size; (void)ws_size;
    const float* price  = (const float*)d_in[0];
    const float* tweets = (const float*)d_in[1];
    const int*   counts = (const int*)d_in[2];
    const int*   ei     = (const int*)d_in[3];
    const float* pg_Wi = (const float*)d_in[5];
    const float* pg_Wh = (const float*)d_in[6];
    const float* pg_bi = (const float*)d_in[7];
    const float* pg_bh = (const float*)d_in[8];
    const float* tg_Wi = (const float*)d_in[9];
    const float* tg_Wh = (const float*)d_in[10];
    const float* tg_bi = (const float*)d_in[11];
    const float* tg_bh = (const float*)d_in[12];
    const float* dg_Wi = (const float*)d_in[13];
    const float* dg_Wh = (const float*)d_in[14];
    const float* dg_bi = (const float*)d_in[15];
    const float* dg_bh = (const float*)d_in[16];
    const float* bil_A = (const float*)d_in[17];
    const float* bil_b = (const float*)d_in[18];
    const float* gnn_W = (const float*)d_in[19];
    const float* gnn_b = (const float*)d_in[20];
    const float* fc1_W = (const float*)d_in[21];
    const float* fc1_b = (const float*)d_in[22];
    const float* ln1_g = (const float*)d_in[23];
    const float* ln1_b = (const float*)d_in[24];
    const float* fc2_W = (const float*)d_in[25];
    const float* fc2_b = (const float*)d_in[26];
    const float* ln2_g = (const float*)d_in[27];
    const float* ln2_b = (const float*)d_in[28];
    const float* mlp_W1 = (const float*)d_in[29];
    const float* mlp_b1 = (const float*)d_in[30];
    const float* mlp_W2 = (const float*)d_in[31];
    const float* mlp_b2 = (const float*)d_in[32];

    float* ws      = (float*)d_ws;
    float* x_price = ws;                   // 4000*64   = 256000
    float* news    = ws + 256000;          // 20000*64  = 1280000
    float* text    = ws + 1536000;         // 4000*64
    float* ft      = ws + 1792000;         // 4000*64
    float* agg     = ws + 2048000;         // 8*500*64  = 256000
    float* deg     = ws + 2304000;         // 512
    short* Wf_hi   = (short*)(ws + 2304512);           // 98304 shorts
    short* Wf_lo   = Wf_hi  + 98304;
    short* Whp_hi  = Wf_lo  + 98304;                   // 2*12*64*8 = 12288
    short* Whp_lo  = Whp_hi + 12288;
    short* Bf_hi   = Whp_lo + 12288;                   // 512*64*8 = 262144
    short* Bf_lo   = Bf_hi  + 262144;
    short* Wht_hi  = Bf_lo  + 262144;                  // 12288
    short* Wht_lo  = Wht_hi + 12288;

    hipMemsetAsync(agg, 0, (256000 + 512)*sizeof(float), stream);

    wfrag_prep_kernel<<<NKT*NNT, 64, 0, stream>>>(tg_Wi, Wf_hi, Wf_lo);
    wfrag_prep_kernel<<<2*NNT, 64, 0, stream>>>(pg_Wh, Whp_hi, Whp_lo);
    wfrag_prep_kernel<<<2*NNT, 64, 0, stream>>>(tg_Wh, Wht_hi, Wht_lo);
    bilfrag_prep_kernel<<<128*4, 64, 0, stream>>>(bil_A, Bf_hi, Bf_lo);

    price_gru_mfma_kernel<<<NS/PSEQ, 256, 0, stream>>>(price, pg_Wi, Whp_hi, Whp_lo,
                                                       pg_bi, pg_bh, x_price);
    tweet_gru_kernel<<<NTt/TG, 256, 0, stream>>>(tweets, counts, Wf_hi, Wf_lo,
                                                 Wht_hi, Wht_lo, tg_bi, tg_bh, news);
    date_gru_kernel<<<NS, 192, 0, stream>>>(news, dg_Wi, dg_Wh, dg_bi, dg_bh, text);
    bilinear_mfma_kernel<<<NS/16, 256, 0, stream>>>(text, x_price, Bf_hi, Bf_lo, bil_b, ft);
    deg_kernel<<<(Eq+255)/256, 256, 0, stream>>>(ei, deg);
    agg_kernel<<<(Eq*Hq)/256, 256, 0, stream>>>(ei, ft, agg);
    head_kernel<<<NS, 64, 0, stream>>>(ft, agg, deg,
                                       gnn_W, gnn_b, fc1_W, fc1_b, ln1_g, ln1_b,
                                       fc2_W, fc2_b, ln2_g, ln2_b,
                                       mlp_W1, mlp_b1, mlp_W2, mlp_b2,
                                       (float*)d_out);
}

// Round 4
// 848.247 us; speedup vs baseline: 1.1143x; 1.0070x over previous
//
#include <hip/hip_runtime.h>
#include <math.h>

#define Bq 8
#define Sq 500
#define Tq 30
#define Dq 5
#define Kq 10
#define Hq 64
#define TWq 512
#define Eq 8000
#define NS (Bq*Sq)      // 4000
#define NTt (NS*Dq)     // 20000
#define G3 (3*Hq)       // 192
#define TG 4            // tweet seqs per block

#define MR 48           // padded GEMM rows (TG*Kq=40 -> 48)
#define KC 64           // K chunk staged per iteration
#define XPITCH 72       // LDS row pitch in bf16 elems (144B: 2-way bank alias = free)
#define XGP 196         // xg fp32 pitch (196%32=4 -> conflict-free epilogue)
#define NKT (TWq/32)    // 16 k-tiles of 32
#define NNT (G3/16)     // 12 n-tiles of 16
#define PSEQ 16         // price seqs per block

#define XROWS 40        // rows of xg actually used (TG*Kq)
#define STG_PLANE (MR*XPITCH)        // 3456 shorts per hi/lo plane
#define STG_BUF  (2*STG_PLANE)       // 6912 shorts per buffer (hi+lo)

typedef __attribute__((ext_vector_type(8))) short short8_t;
typedef __attribute__((ext_vector_type(4))) float float4_t;

__device__ __forceinline__ float fsig(float x) {
    return 1.0f / (1.0f + __expf(-x));
}
__device__ __forceinline__ float ftanh(float x) {
    // 1 - 2/(e^{2x}+1); exact limits at +-inf
    return 1.0f - 2.0f / (__expf(2.0f * x) + 1.0f);
}

__device__ __forceinline__ float wave_sum64(float v) {
    #pragma unroll
    for (int off = 32; off; off >>= 1) v += __shfl_xor(v, off, 64);
    return v;
}

__device__ __forceinline__ short f32_to_bf16_rn(float f) {
    union { float f; unsigned u; } v; v.f = f;
    unsigned r = v.u + 0x7fffu + ((v.u >> 16) & 1u);
    return (short)(r >> 16);
}
__device__ __forceinline__ float bf16_to_f32(short s) {
    union { unsigned u; float f; } v; v.u = ((unsigned)(unsigned short)s) << 16;
    return v.f;
}

// ---- prep: [K x 192] row-major -> MFMA B-frag order, split hi/lo bf16 ------
// Wf[kt][nt][lane][j] = W[kt*32 + (lane>>4)*8 + j][nt*16 + (lane&15)]
// grid = (K/32)*NNT blocks of 64
__global__ __launch_bounds__(64)
void wfrag_prep_kernel(const float* __restrict__ Wi,
                       short* __restrict__ Wf_hi, short* __restrict__ Wf_lo) {
    const int kt = blockIdx.x / NNT;
    const int nt = blockIdx.x - kt*NNT;
    const int lane = threadIdx.x;
    const int quad = lane >> 4, l16 = lane & 15;
    short h[8], l[8];
    #pragma unroll
    for (int j = 0; j < 8; j++) {
        int k = kt*32 + quad*8 + j;
        int n = nt*16 + l16;
        float w = Wi[(size_t)k*G3 + n];
        short hi = f32_to_bf16_rn(w);
        short lo = f32_to_bf16_rn(w - bf16_to_f32(hi));
        h[j] = hi; l[j] = lo;
    }
    size_t off = ((size_t)blockIdx.x*64 + lane)*8;
    *(short8_t*)(Wf_hi + off) = *(const short8_t*)h;
    *(short8_t*)(Wf_lo + off) = *(const short8_t*)l;
}

// ---- prep for bil_A: B[kidx][n] = bil_A[n*4096 + kidx]; grid 128*4 ---------
__global__ __launch_bounds__(64)
void bilfrag_prep_kernel(const float* __restrict__ A,
                         short* __restrict__ Bf_hi, short* __restrict__ Bf_lo) {
    const int kt = blockIdx.x >> 2;        // 0..127
    const int nt = blockIdx.x & 3;         // 0..3
    const int lane = threadIdx.x;
    const int quad = lane >> 4, l16 = lane & 15;
    short h[8], l[8];
    #pragma unroll
    for (int j = 0; j < 8; j++) {
        int kidx = kt*32 + quad*8 + j;
        int n = nt*16 + l16;
        float w = A[(size_t)n*4096 + kidx];
        short hi = f32_to_bf16_rn(w);
        h[j] = hi; l[j] = f32_to_bf16_rn(w - bf16_to_f32(hi));
    }
    size_t off = ((size_t)blockIdx.x*64 + lane)*8;
    *(short8_t*)(Bf_hi + off) = *(const short8_t*)h;
    *(short8_t*)(Bf_lo + off) = *(const short8_t*)l;
}

// -------- price GRU via MFMA: 16 seqs/block, gate-aligned n-tiles -----------
__global__ __launch_bounds__(256)
void price_gru_mfma_kernel(const float* __restrict__ price,
                           const float* __restrict__ Wi,
                           const short* __restrict__ Whf_hi, const short* __restrict__ Whf_lo,
                           const float* __restrict__ bi, const float* __restrict__ bh,
                           float* __restrict__ xout) {
    __shared__ __align__(16) float price_s[PSEQ*90];
    __shared__ __align__(16) short h_hi[PSEQ*72];
    __shared__ __align__(16) short h_lo[PSEQ*72];
    const int tid = threadIdx.x;
    const int n0 = blockIdx.x * PSEQ;
    const int wv = tid >> 6;
    const int lane = tid & 63;
    const int quad = lane >> 4;
    const int l16 = lane & 15;
    const int u = wv*16 + l16;
    for (int i = tid; i < PSEQ*90; i += 256) price_s[i] = price[(size_t)n0*90 + i];
    for (int i = tid; i < PSEQ*72; i += 256) { h_hi[i] = 0; h_lo[i] = 0; }
    float wir[3], wiz[3], win[3];
    #pragma unroll
    for (int k = 0; k < 3; k++) {
        wir[k] = Wi[k*G3 + u];
        wiz[k] = Wi[k*G3 + 64 + u];
        win[k] = Wi[k*G3 + 128 + u];
    }
    const float cbr = bi[u] + bh[u];
    const float cbz = bi[64+u] + bh[64+u];
    const float bin = bi[128+u];
    const float bhn = bh[128+u];
    short8_t bfh[2][3], bfl[2][3];
    #pragma unroll
    for (int kt = 0; kt < 2; kt++)
        #pragma unroll
        for (int g = 0; g < 3; g++) {
            size_t off = (((size_t)kt*NNT + (g*4 + wv))*64 + lane)*8;
            bfh[kt][g] = *(const short8_t*)(Whf_hi + off);
            bfl[kt][g] = *(const short8_t*)(Whf_lo + off);
        }
    float hprev[4] = {0.f,0.f,0.f,0.f}, sum[4] = {0.f,0.f,0.f,0.f};
    __syncthreads();
    for (int t = 0; t < Tq; t++) {
        short8_t ah[2], al[2];
        #pragma unroll
        for (int kt = 0; kt < 2; kt++) {
            int addr = l16*72 + kt*32 + quad*8;
            ah[kt] = *(const short8_t*)&h_hi[addr];
            al[kt] = *(const short8_t*)&h_lo[addr];
        }
        float4_t accr = {0.f,0.f,0.f,0.f}, accz = {0.f,0.f,0.f,0.f}, accn = {0.f,0.f,0.f,0.f};
        #pragma unroll
        for (int kt = 0; kt < 2; kt++) {
            accr = __builtin_amdgcn_mfma_f32_16x16x32_bf16(ah[kt], bfh[kt][0], accr, 0,0,0);
            accr = __builtin_amdgcn_mfma_f32_16x16x32_bf16(ah[kt], bfl[kt][0], accr, 0,0,0);
            accr = __builtin_amdgcn_mfma_f32_16x16x32_bf16(al[kt], bfh[kt][0], accr, 0,0,0);
            accz = __builtin_amdgcn_mfma_f32_16x16x32_bf16(ah[kt], bfh[kt][1], accz, 0,0,0);
            accz = __builtin_amdgcn_mfma_f32_16x16x32_bf16(ah[kt], bfl[kt][1], accz, 0,0,0);
            accz = __builtin_amdgcn_mfma_f32_16x16x32_bf16(al[kt], bfh[kt][1], accz, 0,0,0);
            accn = __builtin_amdgcn_mfma_f32_16x16x32_bf16(ah[kt], bfh[kt][2], accn, 0,0,0);
            accn = __builtin_amdgcn_mfma_f32_16x16x32_bf16(ah[kt], bfl[kt][2], accn, 0,0,0);
            accn = __builtin_amdgcn_mfma_f32_16x16x32_bf16(al[kt], bfl[kt][2], accn, 0,0,0);
        }
        __syncthreads();   // A-frag reads done before h is rewritten
        #pragma unroll
        for (int r = 0; r < 4; r++) {
            const int s = quad*4 + r;
            float p0 = price_s[s*90 + t*3 + 0];
            float p1 = price_s[s*90 + t*3 + 1];
            float p2 = price_s[s*90 + t*3 + 2];
            float xr = fmaf(p2, wir[2], fmaf(p1, wir[1], fmaf(p0, wir[0], cbr)));
            float xz = fmaf(p2, wiz[2], fmaf(p1, wiz[1], fmaf(p0, wiz[0], cbz)));
            float xn = fmaf(p2, win[2], fmaf(p1, win[1], fmaf(p0, win[0], bin)));
            float rg = fsig(xr + accr[r]);
            float zg = fsig(xz + accz[r]);
            float ng = ftanh(xn + rg*(accn[r] + bhn));
            float h = (1.0f - zg)*ng + zg*hprev[r];
            hprev[r] = h; sum[r] += h;
            short hh = f32_to_bf16_rn(h);
            h_hi[s*72 + u] = hh;
            h_lo[s*72 + u] = f32_to_bf16_rn(h - bf16_to_f32(hh));
        }
        __syncthreads();   // h writes visible before next A-frag read
    }
    #pragma unroll
    for (int r = 0; r < 4; r++)
        xout[(size_t)(n0 + quad*4 + r)*Hq + u] = sum[r];
}

// ------------- tweet GRU: MFMA split-bf16 projection + MFMA recurrence ------
__global__ __launch_bounds__(256, 4)
void tweet_gru_kernel(const float* __restrict__ tweets,
                      const int* __restrict__ counts,
                      const short* __restrict__ Wf_hi, const short* __restrict__ Wf_lo,
                      const short* __restrict__ Wht_hi, const short* __restrict__ Wht_lo,
                      const float* __restrict__ bi, const float* __restrict__ bh,
                      float* __restrict__ news) {
    __shared__ __align__(16) char smem[XROWS*XGP*4];   // 31360 B
    __shared__ __align__(16) short rh_hi[16*72];       // recurrence h A-rows
    __shared__ __align__(16) short rh_lo[16*72];
    __shared__ int len_s[TG];
    __shared__ int tmax_s;
    short* stg = (short*)smem;     // [2 bufs][hi 3456 | lo 3456] shorts = 27648 B
    float* xg  = (float*)smem;     // [XROWS][XGP] f32, aliases staging

    const int tid  = threadIdx.x;
    const int n0   = blockIdx.x * TG;
    const int wave = tid >> 6;
    const int lane = tid & 63;
    const int quad = lane >> 4;
    const int l16  = lane & 15;

    if (tid < TG) {
        int c = counts[n0 + tid];
        len_s[tid] = c < 0 ? 0 : (c > Kq ? Kq : c);
    }
    for (int i = tid; i < 16*72; i += 256) { rh_hi[i] = 0; rh_lo[i] = 0; }
    __syncthreads();
    if (tid == 0) {
        int m01 = len_s[0] > len_s[1] ? len_s[0] : len_s[1];
        int m23 = len_s[2] > len_s[3] ? len_s[2] : len_s[3];
        tmax_s = m01 > m23 ? m01 : m23;
    }

    // ---- hoisted staging descriptors (640 float4 items, stride 256) --------
    const float* gp[3];
    int lofs[3];
    bool val[3];
    #pragma unroll
    for (int j = 0; j < 3; j++) {
        const int ii = tid + j*256;
        const bool ok = ii < TG*Kq*(KC/4);        // < 640
        const int i = ok ? ii : 0;
        const int row = i >> 4;
        const int c4  = i & 15;
        const int s   = (row*205) >> 11;          // row/10 for row<48
        const int t   = row - s*10;
        val[j]  = ok && (t < len_s[s]);
        gp[j]   = tweets + (((size_t)(n0+s))*Kq + t)*TWq + c4*4;
        lofs[j] = row*XPITCH + c4*4;
    }

    float4_t acc[3][3];   // [mt][ntl]
    #pragma unroll
    for (int a = 0; a < 3; a++)
        #pragma unroll
        for (int b = 0; b < 3; b++)
            acc[a][b] = (float4_t){0.f, 0.f, 0.f, 0.f};

    // ---- prologue: stage chunk 0 into buffer 0 ----
    #pragma unroll
    for (int j = 0; j < 3; j++) if (val[j]) {
        float4 v = *(const float4*)(gp[j]);
        float f[4] = {v.x, v.y, v.z, v.w};
        short hh[4], ll[4];
        #pragma unroll
        for (int q = 0; q < 4; q++) {
            short hi = f32_to_bf16_rn(f[q]);
            hh[q] = hi;
            ll[q] = f32_to_bf16_rn(f[q] - bf16_to_f32(hi));
        }
        *(short4*)&stg[lofs[j]]             = *(const short4*)hh;
        *(short4*)&stg[STG_PLANE + lofs[j]] = *(const short4*)ll;
    }
    __syncthreads();

    for (int ch = 0; ch < TWq/KC; ch++) {
        const int cur = ch & 1;
        // (1) issue next chunk's global loads early
        float4 v[3];
        if (ch < TWq/KC - 1) {
            #pragma unroll
            for (int j = 0; j < 3; j++) if (val[j])
                v[j] = *(const float4*)(gp[j] + (ch+1)*KC);
        }
        // (2) MFMA on current buffer
        const short* xh = stg + cur*STG_BUF;
        const short* xl = xh + STG_PLANE;
        #pragma unroll
        for (int ks = 0; ks < KC/32; ks++) {
            const int kt = ch*(KC/32) + ks;
            short8_t bh_[3], bl_[3];
            #pragma unroll
            for (int ntl = 0; ntl < 3; ntl++) {
                size_t off = (((size_t)kt*NNT + (wave*3 + ntl))*64 + lane)*8;
                bh_[ntl] = *(const short8_t*)(Wf_hi + off);
                bl_[ntl] = *(const short8_t*)(Wf_lo + off);
            }
            short8_t ah_[3], al_[3];
            #pragma unroll
            for (int mt = 0; mt < 3; mt++) {
                int addr = (mt*16 + l16)*XPITCH + ks*32 + quad*8;
                ah_[mt] = *(const short8_t*)&xh[addr];
                al_[mt] = *(const short8_t*)&xl[addr];
            }
            #pragma unroll
            for (int mt = 0; mt < 3; mt++)
                #pragma unroll
                for (int ntl = 0; ntl < 3; ntl++) {
                    acc[mt][ntl] = __builtin_amdgcn_mfma_f32_16x16x32_bf16(ah_[mt], bh_[ntl], acc[mt][ntl], 0, 0, 0);
                    acc[mt][ntl] = __builtin_amdgcn_mfma_f32_16x16x32_bf16(ah_[mt], bl_[ntl], acc[mt][ntl], 0, 0, 0);
                    acc[mt][ntl] = __builtin_amdgcn_mfma_f32_16x16x32_bf16(al_[mt], bh_[ntl], acc[mt][ntl], 0, 0, 0);
                }
        }
        // (3) convert + write next chunk into the other buffer
        if (ch < TWq/KC - 1) {
            short* yh = stg + (cur^1)*STG_BUF;
            short* yl = yh + STG_PLANE;
            #pragma unroll
            for (int j = 0; j < 3; j++) if (val[j]) {
                float f[4] = {v[j].x, v[j].y, v[j].z, v[j].w};
                short hh[4], ll[4];
                #pragma unroll
                for (int q = 0; q < 4; q++) {
                    short hi = f32_to_bf16_rn(f[q]);
                    hh[q] = hi;
                    ll[q] = f32_to_bf16_rn(f[q] - bf16_to_f32(hi));
                }
                *(short4*)&yh[lofs[j]] = *(const short4*)hh;
                *(short4*)&yl[lofs[j]] = *(const short4*)ll;
            }
        }
        __syncthreads();   // next buffer ready; current buffer reads done
    }

    // ---- epilogue: acc -> xg (only the 40 live rows) ----
    #pragma unroll
    for (int ntl = 0; ntl < 3; ntl++) {
        const int col = (wave*3 + ntl)*16 + l16;
        const float bic = bi[col];
        #pragma unroll
        for (int mt = 0; mt < 3; mt++) {
            const int row0 = mt*16 + quad*4;
            if (row0 < XROWS) {
                #pragma unroll
                for (int r2 = 0; r2 < 4; r2++)
                    xg[(row0 + r2)*XGP + col] = acc[mt][ntl][r2] + bic;
            }
        }
    }

    // ---- recurrence via MFMA (gate-aligned) ----
    const int u = wave*16 + l16;
    short8_t tbh[2][3], tbl[2][3];
    #pragma unroll
    for (int kt = 0; kt < 2; kt++)
        #pragma unroll
        for (int g = 0; g < 3; g++) {
            size_t off = (((size_t)kt*NNT + (g*4 + wave))*64 + lane)*8;
            tbh[kt][g] = *(const short8_t*)(Wht_hi + off);
            tbl[kt][g] = *(const short8_t*)(Wht_lo + off);
        }
    const float bhr = bh[u];
    const float bhz = bh[64+u];
    const float bhn = bh[128+u];
    int lp[4];
    #pragma unroll
    for (int r = 0; r < 4; r++) lp[r] = len_s[r];
    float hprev[4] = {0.f,0.f,0.f,0.f}, sum[4] = {0.f,0.f,0.f,0.f};
    const int tmax = tmax_s;
    for (int t = 0; t < tmax; t++) {
        const int ha = l16*72;
        short8_t ah0 = *(const short8_t*)&rh_hi[ha + quad*8];
        short8_t ah1 = *(const short8_t*)&rh_hi[ha + 32 + quad*8];
        short8_t al0 = *(const short8_t*)&rh_lo[ha + quad*8];
        short8_t al1 = *(const short8_t*)&rh_lo[ha + 32 + quad*8];
        float4_t ar = {0.f,0.f,0.f,0.f}, az = {0.f,0.f,0.f,0.f}, an = {0.f,0.f,0.f,0.f};
        ar = __builtin_amdgcn_mfma_f32_16x16x32_bf16(ah0, tbh[0][0], ar, 0,0,0);
        ar = __builtin_amdgcn_mfma_f32_16x16x32_bf16(ah0, tbl[0][0], ar, 0,0,0);
        ar = __builtin_amdgcn_mfma_f32_16x16x32_bf16(al0, tbh[0][0], ar, 0,0,0);
        ar = __builtin_amdgcn_mfma_f32_16x16x32_bf16(ah1, tbh[1][0], ar, 0,0,0);
        ar = __builtin_amdgcn_mfma_f32_16x16x32_bf16(ah1, tbl[1][0], ar, 0,0,0);
        ar = __builtin_amdgcn_mfma_f32_16x16x32_bf16(al1, tbh[1][0], ar, 0,0,0);
        az = __builtin_amdgcn_mfma_f32_16x16x32_bf16(ah0, tbh[0][1], az, 0,0,0);
        az = __builtin_amdgcn_mfma_f32_16x16x32_bf16(ah0, tbl[0][1], az, 0,0,0);
        az = __builtin_amdgcn_mfma_f32_16x16x32_bf16(al0, tbh[0][1], az, 0,0,0);
        az = __builtin_amdgcn_mfma_f32_16x16x32_bf16(ah1, tbh[1][1], az, 0,0,0);
        az = __builtin_amdgcn_mfma_f32_16x16x32_bf16(ah1, tbl[1][1], az, 0,0,0);
        az = __builtin_amdgcn_mfma_f32_16x16x32_bf16(al1, tbh[1][1], az, 0,0,0);
        an = __builtin_amdgcn_mfma_f32_16x16x32_bf16(ah0, tbh[0][2], an, 0,0,0);
        an = __builtin_amdgcn_mfma_f32_16x16x32_bf16(ah0, tbl[0][2], an, 0,0,0);
        an = __builtin_amdgcn_mfma_f32_16x16x32_bf16(al0, tbh[0][2], an, 0,0,0);
        an = __builtin_amdgcn_mfma_f32_16x16x32_bf16(ah1, tbh[1][2], an, 0,0,0);
        an = __builtin_amdgcn_mfma_f32_16x16x32_bf16(ah1, tbl[1][2], an, 0,0,0);
        an = __builtin_amdgcn_mfma_f32_16x16x32_bf16(al1, tbl[1][2], an, 0,0,0);
        __syncthreads();   // A-frag reads (and epilogue xg writes at t=0) done
        if (quad == 0) {
            #pragma unroll
            for (int r = 0; r < 4; r++) {
                if (t < lp[r]) {
                    const float* xr = &xg[(r*Kq + t)*XGP];
                    float rg = fsig(xr[u]        + ar[r] + bhr);
                    float zg = fsig(xr[Hq+u]     + az[r] + bhz);
                    float ng = ftanh(xr[2*Hq+u]  + rg*(an[r] + bhn));
                    float hn = (1.0f - zg)*ng + zg*hprev[r];
                    hprev[r] = hn; sum[r] += hn;
                    short hh = f32_to_bf16_rn(hn);
                    rh_hi[r*72 + u] = hh;
                    rh_lo[r*72 + u] = f32_to_bf16_rn(hn - bf16_to_f32(hh));
                }
            }
        }
        __syncthreads();   // h writes visible before next A-frag read
    }
    if (quad == 0) {
        #pragma unroll
        for (int r = 0; r < 4; r++)
            news[(size_t)(n0 + r)*Hq + u] = sum[r];
    }
}

// ---------------- date GRU: one block (192 thr) per sequence ----------------
__global__ __launch_bounds__(192)
void date_gru_kernel(const float* __restrict__ news,
                     const float* __restrict__ Wi, const float* __restrict__ Wh,
                     const float* __restrict__ bi, const float* __restrict__ bh,
                     float* __restrict__ text) {
    __shared__ __align__(16) float nw_s[Dq*Hq];
    __shared__ __align__(16) float h_s[Hq];
    __shared__ __align__(16) float xg_s[G3];
    __shared__ __align__(16) float hg_s[G3];
    const int n = blockIdx.x;
    const int g = threadIdx.x;
    for (int i = g; i < Dq*Hq; i += 192) nw_s[i] = news[(size_t)n*Dq*Hq + i];
    float wi[Hq], wh[Hq];
    #pragma unroll
    for (int j = 0; j < Hq; j++) { wi[j] = Wi[j*G3+g]; wh[j] = Wh[j*G3+g]; }
    const float big = bi[g], bhg = bh[g];
    if (g < Hq) h_s[g] = 0.0f;
    float hreg = 0.0f, sum = 0.0f;
    __syncthreads();
    for (int t = 0; t < Dq; t++) {
        float a0=0.f,a1=0.f,a2=0.f,a3=0.f, b0=0.f,b1=0.f,b2=0.f,b3=0.f;
        #pragma unroll
        for (int j = 0; j < Hq; j += 4) {
            float4 nv = *(const float4*)&nw_s[t*Hq + j];
            float4 hv = *(const float4*)&h_s[j];
            a0 = fmaf(nv.x, wi[j+0], a0);
            a1 = fmaf(nv.y, wi[j+1], a1);
            a2 = fmaf(nv.z, wi[j+2], a2);
            a3 = fmaf(nv.w, wi[j+3], a3);
            b0 = fmaf(hv.x, wh[j+0], b0);
            b1 = fmaf(hv.y, wh[j+1], b1);
            b2 = fmaf(hv.z, wh[j+2], b2);
            b3 = fmaf(hv.w, wh[j+3], b3);
        }
        xg_s[g] = big + ((a0+a1)+(a2+a3));
        hg_s[g] = bhg + ((b0+b1)+(b2+b3));
        __syncthreads();
        if (g < Hq) {
            float r  = fsig(xg_s[g]      + hg_s[g]);
            float z  = fsig(xg_s[Hq+g]   + hg_s[Hq+g]);
            float nn = ftanh(xg_s[2*Hq+g] + r*hg_s[2*Hq+g]);
            hreg = (1.0f - z)*nn + z*hreg;
            sum += hreg;
            h_s[g] = hreg;
        }
        __syncthreads();
    }
    if (g < Hq) text[(size_t)n*Hq + g] = sum;
}

// -------- bilinear via MFMA: C[n,k] = tanh(sum_ij P[n,ij] A2[k,ij] + b_k) ---
#define TP 68
#define XP 72
__global__ __launch_bounds__(256)
void bilinear_mfma_kernel(const float* __restrict__ text, const float* __restrict__ x,
                          const short* __restrict__ Bf_hi, const short* __restrict__ Bf_lo,
                          const float* __restrict__ bb, float* __restrict__ ft) {
    __shared__ __align__(16) float t_s[16*TP];
    __shared__ __align__(16) float x_s[16*XP];
    const int tid = threadIdx.x;
    const int n0 = blockIdx.x * 16;
    const int wv = tid >> 6, lane = tid & 63, quad = lane >> 4, l16 = lane & 15;
    for (int i = tid; i < 16*64; i += 256) {
        int r = i >> 6, c = i & 63;
        t_s[r*TP + c] = text[(size_t)(n0 + r)*Hq + c];
        x_s[r*XP + c] = x[(size_t)(n0 + r)*Hq + c];
    }
    float4_t acc = {0.f,0.f,0.f,0.f};
    __syncthreads();
    for (int kt = 0; kt < 128; kt++) {
        const int i  = kt >> 1;
        const int j0 = (kt & 1)*32 + quad*8;
        size_t boff = (((size_t)kt*4 + wv)*64 + lane)*8;
        short8_t bh_ = *(const short8_t*)(Bf_hi + boff);
        short8_t bl_ = *(const short8_t*)(Bf_lo + boff);
        float ti = t_s[l16*TP + i];
        float xv[8];
        *(float4*)&xv[0] = *(const float4*)&x_s[l16*XP + j0];
        *(float4*)&xv[4] = *(const float4*)&x_s[l16*XP + j0 + 4];
        short ph[8], pl[8];
        #pragma unroll
        for (int jj = 0; jj < 8; jj++) {
            float p = ti * xv[jj];
            short hi = f32_to_bf16_rn(p);
            ph[jj] = hi;
            pl[jj] = f32_to_bf16_rn(p - bf16_to_f32(hi));
        }
        short8_t ah = *(const short8_t*)ph;
        short8_t al = *(const short8_t*)pl;
        acc = __builtin_amdgcn_mfma_f32_16x16x32_bf16(ah, bh_, acc, 0,0,0);
        acc = __builtin_amdgcn_mfma_f32_16x16x32_bf16(ah, bl_, acc, 0,0,0);
        acc = __builtin_amdgcn_mfma_f32_16x16x32_bf16(al, bh_, acc, 0,0,0);
    }
    const int col = wv*16 + l16;
    const float bk = bb[col];
    #pragma unroll
    for (int r = 0; r < 4; r++) {
        int n = quad*4 + r;
        ft[(size_t)(n0 + n)*Hq + col] = ftanh(acc[r] + bk);
    }
}

// --------------- GNN edge preprocessing: count / scan / scatter -------------
__global__ void count_kernel(const int* __restrict__ ei, int* __restrict__ cnt) {
    int e = blockIdx.x*256 + threadIdx.x;
    if (e < Eq) atomicAdd(&cnt[ei[Eq + e]], 1);
}

// single block of 512 threads: exclusive scan of cnt[0..Sq) -> off[0..Sq]
__global__ __launch_bounds__(512)
void scan_kernel(const int* __restrict__ cnt, int* __restrict__ off,
                 int* __restrict__ cursor) {
    __shared__ int buf[512];
    const int tid = threadIdx.x;
    int v = (tid < Sq) ? cnt[tid] : 0;
    buf[tid] = v;
    __syncthreads();
    #pragma unroll
    for (int d = 1; d < 512; d <<= 1) {
        int t = (tid >= d) ? buf[tid - d] : 0;
        __syncthreads();
        buf[tid] += t;
        __syncthreads();
    }
    if (tid <= Sq) {
        int excl = buf[tid] - v;           // v=0 for tid==Sq -> total
        off[tid] = excl;
        if (tid < Sq) cursor[tid] = excl;
    }
}

__global__ void scatter_kernel(const int* __restrict__ ei, int* __restrict__ cursor,
                               int* __restrict__ sorted_src) {
    int e = blockIdx.x*256 + threadIdx.x;
    if (e < Eq) {
        int dst = ei[Eq + e];
        int p = atomicAdd(&cursor[dst], 1);
        sorted_src[p] = ei[e];
    }
}

// ------------------------------ head ----------------------------------------
// aggregation fused in: block n=(b,s) sums ft rows of its CSR edge segment.
__global__ __launch_bounds__(64)
void head_kernel(const float* __restrict__ ft,
                 const int* __restrict__ off, const int* __restrict__ sorted_src,
                 const float* __restrict__ gnn_W, const float* __restrict__ gnn_b,
                 const float* __restrict__ fc1_W, const float* __restrict__ fc1_b,
                 const float* __restrict__ ln1_g, const float* __restrict__ ln1_b,
                 const float* __restrict__ fc2_W, const float* __restrict__ fc2_b,
                 const float* __restrict__ ln2_g, const float* __restrict__ ln2_b,
                 const float* __restrict__ mlp_W1, const float* __restrict__ mlp_b1,
                 const float* __restrict__ mlp_W2, const float* __restrict__ mlp_b2,
                 float* __restrict__ out) {
    __shared__ __align__(16) float a_s[Hq];
    __shared__ __align__(16) float in_s[2*Hq];
    __shared__ __align__(16) float t_s[Hq];
    const int n = blockIdx.x;
    const int b = n / Sq;
    const int s = n - b*Sq;
    const int u = threadIdx.x;
    const int o0 = off[s], o1 = off[s+1];
    const float* ftb = ft + (size_t)b*Sq*Hq;
    float acc = 0.0f;
    for (int e = o0; e < o1; ++e)
        acc += ftb[(size_t)sorted_src[e]*Hq + u];
    const float denom = (o1 - o0) > 1 ? (float)(o1 - o0) : 1.0f;
    a_s[u]  = acc / denom;
    in_s[u] = ft[(size_t)n*Hq + u];
    __syncthreads();
    {
        float a0=0.f,a1=0.f,a2=0.f,a3=0.f;
        #pragma unroll
        for (int j = 0; j < Hq; j += 4) {
            a0 = fmaf(a_s[j+0], gnn_W[(j+0)*Hq + u], a0);
            a1 = fmaf(a_s[j+1], gnn_W[(j+1)*Hq + u], a1);
            a2 = fmaf(a_s[j+2], gnn_W[(j+2)*Hq + u], a2);
            a3 = fmaf(a_s[j+3], gnn_W[(j+3)*Hq + u], a3);
        }
        in_s[Hq+u] = ftanh(gnn_b[u] + ((a0+a1)+(a2+a3)));
    }
    __syncthreads();
    float v;
    {
        float a0=0.f,a1=0.f,a2=0.f,a3=0.f;
        #pragma unroll
        for (int j = 0; j < 2*Hq; j += 4) {
            a0 = fmaf(in_s[j+0], fc1_W[(j+0)*Hq + u], a0);
            a1 = fmaf(in_s[j+1], fc1_W[(j+1)*Hq + u], a1);
            a2 = fmaf(in_s[j+2], fc1_W[(j+2)*Hq + u], a2);
            a3 = fmaf(in_s[j+3], fc1_W[(j+3)*Hq + u], a3);
        }
        v = fc1_b[u] + ((a0+a1)+(a2+a3));
        float m = wave_sum64(v) * (1.0f/Hq);
        float d = v - m;
        float var = wave_sum64(d*d) * (1.0f/Hq);
        v = fmaxf(d * rsqrtf(var + 1e-5f) * ln1_g[u] + ln1_b[u], 0.0f);
    }
    t_s[u] = v;
    __syncthreads();
    {
        float a0=0.f,a1=0.f,a2=0.f,a3=0.f;
        #pragma unroll
        for (int j = 0; j < Hq; j += 4) {
            a0 = fmaf(t_s[j+0], fc2_W[(j+0)*Hq + u], a0);
            a1 = fmaf(t_s[j+1], fc2_W[(j+1)*Hq + u], a1);
            a2 = fmaf(t_s[j+2], fc2_W[(j+2)*Hq + u], a2);
            a3 = fmaf(t_s[j+3], fc2_W[(j+3)*Hq + u], a3);
        }
        v = fc2_b[u] + ((a0+a1)+(a2+a3));
        float m = wave_sum64(v) * (1.0f/Hq);
        float d = v - m;
        float var = wave_sum64(d*d) * (1.0f/Hq);
        v = fmaxf(d * rsqrtf(var + 1e-5f) * ln2_g[u] + ln2_b[u], 0.0f);
    }
    __syncthreads();
    a_s[u] = v;
    __syncthreads();
    {
        float a0=0.f,a1=0.f,a2=0.f,a3=0.f;
        #pragma unroll
        for (int j = 0; j < Hq; j += 4) {
            a0 = fmaf(a_s[j+0], mlp_W1[(j+0)*Hq + u], a0);
            a1 = fmaf(a_s[j+1], mlp_W1[(j+1)*Hq + u], a1);
            a2 = fmaf(a_s[j+2], mlp_W1[(j+2)*Hq + u], a2);
            a3 = fmaf(a_s[j+3], mlp_W1[(j+3)*Hq + u], a3);
        }
        v = fmaxf(mlp_b1[u] + ((a0+a1)+(a2+a3)), 0.0f);
    }
    float p = wave_sum64(v * mlp_W2[u]);
    if (u == 0) out[n] = p + mlp_b2[0];
}

extern "C" void kernel_launch(void* const* d_in, const int* in_sizes, int n_in,
                              void* d_out, int out_size, void* d_ws, size_t ws_size,
                              hipStream_t stream) {
    (void)in_sizes; (void)n_in; (void)out_size; (void)ws_size;
    const float* price  = (const float*)d_in[0];
    const float* tweets = (const float*)d_in[1];
    const int*   counts = (const int*)d_in[2];
    const int*   ei     = (const int*)d_in[3];
    const float* pg_Wi = (const float*)d_in[5];
    const float* pg_Wh = (const float*)d_in[6];
    const float* pg_bi = (const float*)d_in[7];
    const float* pg_bh = (const float*)d_in[8];
    const float* tg_Wi = (const float*)d_in[9];
    const float* tg_Wh = (const float*)d_in[10];
    const float* tg_bi = (const float*)d_in[11];
    const float* tg_bh = (const float*)d_in[12];
    const float* dg_Wi = (const float*)d_in[13];
    const float* dg_Wh = (const float*)d_in[14];
    const float* dg_bi = (const float*)d_in[15];
    const float* dg_bh = (const float*)d_in[16];
    const float* bil_A = (const float*)d_in[17];
    const float* bil_b = (const float*)d_in[18];
    const float* gnn_W = (const float*)d_in[19];
    const float* gnn_b = (const float*)d_in[20];
    const float* fc1_W = (const float*)d_in[21];
    const float* fc1_b = (const float*)d_in[22];
    const float* ln1_g = (const float*)d_in[23];
    const float* ln1_b = (const float*)d_in[24];
    const float* fc2_W = (const float*)d_in[25];
    const float* fc2_b = (const float*)d_in[26];
    const float* ln2_g = (const float*)d_in[27];
    const float* ln2_b = (const float*)d_in[28];
    const float* mlp_W1 = (const float*)d_in[29];
    const float* mlp_b1 = (const float*)d_in[30];
    const float* mlp_W2 = (const float*)d_in[31];
    const float* mlp_b2 = (const float*)d_in[32];

    float* ws      = (float*)d_ws;
    float* x_price = ws;                   // 4000*64   = 256000
    float* news    = ws + 256000;          // 20000*64  = 1280000
    float* text    = ws + 1536000;         // 4000*64
    float* ft      = ws + 1792000;         // 4000*64
    int*   cnt     = (int*)(ws + 2048000); // 500 (zeroed)
    int*   off     = cnt + 512;            // 501
    int*   cursor  = off + 512;            // 500
    int*   sorted  = cursor + 512;         // 8000
    short* Wf_hi   = (short*)(ws + 2304512);           // 98304 shorts
    short* Wf_lo   = Wf_hi  + 98304;
    short* Whp_hi  = Wf_lo  + 98304;                   // 2*12*64*8 = 12288
    short* Whp_lo  = Whp_hi + 12288;
    short* Bf_hi   = Whp_lo + 12288;                   // 512*64*8 = 262144
    short* Bf_lo   = Bf_hi  + 262144;
    short* Wht_hi  = Bf_lo  + 262144;                  // 12288
    short* Wht_lo  = Wht_hi + 12288;

    hipMemsetAsync(cnt, 0, 512*sizeof(int), stream);

    // edge CSR build (independent of the heavy pipeline; runs up front)
    count_kernel<<<(Eq+255)/256, 256, 0, stream>>>(ei, cnt);
    scan_kernel<<<1, 512, 0, stream>>>(cnt, off, cursor);
    scatter_kernel<<<(Eq+255)/256, 256, 0, stream>>>(ei, cursor, sorted);

    wfrag_prep_kernel<<<NKT*NNT, 64, 0, stream>>>(tg_Wi, Wf_hi, Wf_lo);
    wfrag_prep_kernel<<<2*NNT, 64, 0, stream>>>(pg_Wh, Whp_hi, Whp_lo);
    wfrag_prep_kernel<<<2*NNT, 64, 0, stream>>>(tg_Wh, Wht_hi, Wht_lo);
    bilfrag_prep_kernel<<<128*4, 64, 0, stream>>>(bil_A, Bf_hi, Bf_lo);

    price_gru_mfma_kernel<<<NS/PSEQ, 256, 0, stream>>>(price, pg_Wi, Whp_hi, Whp_lo,
                                                       pg_bi, pg_bh, x_price);
    tweet_gru_kernel<<<NTt/TG, 256, 0, stream>>>(tweets, counts, Wf_hi, Wf_lo,
                                                 Wht_hi, Wht_lo, tg_bi, tg_bh, news);
    date_gru_kernel<<<NS, 192, 0, stream>>>(news, dg_Wi, dg_Wh, dg_bi, dg_bh, text);
    bilinear_mfma_kernel<<<NS/16, 256, 0, stream>>>(text, x_price, Bf_hi, Bf_lo, bil_b, ft);
    head_kernel<<<NS, 64, 0, stream>>>(ft, off, sorted,
                                       gnn_W, gnn_b, fc1_W, fc1_b, ln1_g, ln1_b,
                                       fc2_W, fc2_b, ln2_g, ln2_b,
                                       mlp_W1, mlp_b1, mlp_W2, mlp_b2,
                                       (float*)d_out);
}

// Round 5
// 844.312 us; speedup vs baseline: 1.1195x; 1.0047x over previous
//
#include <hip/hip_runtime.h>
#include <math.h>

#define Bq 8
#define Sq 500
#define Tq 30
#define Dq 5
#define Kq 10
#define Hq 64
#define TWq 512
#define Eq 8000
#define NS (Bq*Sq)      // 4000
#define NTt (NS*Dq)     // 20000
#define G3 (3*Hq)       // 192
#define TG 4            // tweet seqs per block

#define MR 48           // padded GEMM rows
#define KC 64           // K chunk staged per iteration
#define XPITCH 72       // LDS row pitch in bf16 elems (144B: 2-way bank alias = free)
#define XGP 196         // xg fp32 pitch (196%32=4 -> conflict-free epilogue)
#define NKT (TWq/32)    // 16 k-tiles of 32
#define NNT (G3/16)     // 12 n-tiles of 16
#define PSEQ 16         // price seqs per block

#define XROWS 40        // max live rows (TG*Kq)
#define STG_PLANE (MR*XPITCH)        // 3456 shorts per hi/lo plane
#define STG_BUF  (2*STG_PLANE)       // 6912 shorts per buffer (hi+lo)

#define PREP_WF   (NKT*NNT)          // 192
#define PREP_WHP  (2*NNT)            // 24
#define PREP_WHT  (2*NNT)            // 24
#define PREP_BIL  512
#define PREP_BLOCKS (PREP_WF+PREP_WHP+PREP_WHT+PREP_BIL)   // 752

typedef __attribute__((ext_vector_type(8))) short short8_t;
typedef __attribute__((ext_vector_type(4))) float float4_t;

__device__ __forceinline__ float fsig(float x) {
    return 1.0f / (1.0f + __expf(-x));
}
__device__ __forceinline__ float ftanh(float x) {
    return 1.0f - 2.0f / (__expf(2.0f * x) + 1.0f);
}

__device__ __forceinline__ float wave_sum64(float v) {
    #pragma unroll
    for (int off = 32; off; off >>= 1) v += __shfl_xor(v, off, 64);
    return v;
}

__device__ __forceinline__ short f32_to_bf16_rn(float f) {
    union { float f; unsigned u; } v; v.f = f;
    unsigned r = v.u + 0x7fffu + ((v.u >> 16) & 1u);
    return (short)(r >> 16);
}
__device__ __forceinline__ float bf16_to_f32(short s) {
    union { unsigned u; float f; } v; v.u = ((unsigned)(unsigned short)s) << 16;
    return v.f;
}

// ---------------- unified prep: 3 W-frag sets + bil_A frags ------------------
// Wf[kt][nt][lane][j] = W[kt*32 + (lane>>4)*8 + j][nt*16 + (lane&15)]
__global__ __launch_bounds__(64)
void prep_all_kernel(const float* __restrict__ tg_Wi, const float* __restrict__ pg_Wh,
                     const float* __restrict__ tg_Wh, const float* __restrict__ bil_A,
                     short* __restrict__ Wf_hi, short* __restrict__ Wf_lo,
                     short* __restrict__ Whp_hi, short* __restrict__ Whp_lo,
                     short* __restrict__ Wht_hi, short* __restrict__ Wht_lo,
                     short* __restrict__ Bf_hi, short* __restrict__ Bf_lo) {
    const int bx = blockIdx.x;
    const int lane = threadIdx.x;
    const int quad = lane >> 4, l16 = lane & 15;
    short h[8], l[8];
    if (bx < PREP_WF + PREP_WHP + PREP_WHT) {
        const float* W; short *dh, *dl; int b;
        if (bx < PREP_WF)               { W = tg_Wi; dh = Wf_hi;  dl = Wf_lo;  b = bx; }
        else if (bx < PREP_WF+PREP_WHP) { W = pg_Wh; dh = Whp_hi; dl = Whp_lo; b = bx - PREP_WF; }
        else                            { W = tg_Wh; dh = Wht_hi; dl = Wht_lo; b = bx - PREP_WF - PREP_WHP; }
        const int kt = b / NNT;
        const int nt = b - kt*NNT;
        #pragma unroll
        for (int j = 0; j < 8; j++) {
            float w = W[(size_t)(kt*32 + quad*8 + j)*G3 + nt*16 + l16];
            short hi = f32_to_bf16_rn(w);
            h[j] = hi; l[j] = f32_to_bf16_rn(w - bf16_to_f32(hi));
        }
        size_t off = ((size_t)b*64 + lane)*8;
        *(short8_t*)(dh + off) = *(const short8_t*)h;
        *(short8_t*)(dl + off) = *(const short8_t*)l;
    } else {
        const int b = bx - (PREP_WF+PREP_WHP+PREP_WHT);
        const int kt = b >> 2;        // 0..127
        const int nt = b & 3;         // 0..3
        #pragma unroll
        for (int j = 0; j < 8; j++) {
            float w = bil_A[(size_t)(nt*16 + l16)*4096 + kt*32 + quad*8 + j];
            short hi = f32_to_bf16_rn(w);
            h[j] = hi; l[j] = f32_to_bf16_rn(w - bf16_to_f32(hi));
        }
        size_t off = ((size_t)b*64 + lane)*8;
        *(short8_t*)(Bf_hi + off) = *(const short8_t*)h;
        *(short8_t*)(Bf_lo + off) = *(const short8_t*)l;
    }
}

// ---------- CSR build in one block: count + scan + scatter via LDS ----------
__global__ __launch_bounds__(512)
void csr_kernel(const int* __restrict__ ei, int* __restrict__ off,
                int* __restrict__ sorted_src) {
    __shared__ int lcnt[512];
    __shared__ int lbuf[512];
    const int tid = threadIdx.x;
    lcnt[tid] = 0;
    __syncthreads();
    for (int e = tid; e < Eq; e += 512)
        atomicAdd(&lcnt[ei[Eq + e]], 1);
    __syncthreads();
    int v = lcnt[tid];
    lbuf[tid] = v;
    __syncthreads();
    #pragma unroll
    for (int d = 1; d < 512; d <<= 1) {
        int t = (tid >= d) ? lbuf[tid - d] : 0;
        __syncthreads();
        lbuf[tid] += t;
        __syncthreads();
    }
    const int excl = lbuf[tid] - v;        // exclusive prefix (v=0 past Sq)
    if (tid <= Sq) off[tid] = excl;
    __syncthreads();
    lcnt[tid] = excl;                      // cursor
    __syncthreads();
    for (int e = tid; e < Eq; e += 512) {
        int dst = ei[Eq + e];
        int p = atomicAdd(&lcnt[dst], 1);
        sorted_src[p] = ei[e];
    }
}

// -------- price GRU via MFMA: 16 seqs/block, gate-aligned n-tiles -----------
__global__ __launch_bounds__(256)
void price_gru_mfma_kernel(const float* __restrict__ price,
                           const float* __restrict__ Wi,
                           const short* __restrict__ Whf_hi, const short* __restrict__ Whf_lo,
                           const float* __restrict__ bi, const float* __restrict__ bh,
                           float* __restrict__ xout) {
    __shared__ __align__(16) float price_s[PSEQ*90];
    __shared__ __align__(16) short h_hi[PSEQ*72];
    __shared__ __align__(16) short h_lo[PSEQ*72];
    const int tid = threadIdx.x;
    const int n0 = blockIdx.x * PSEQ;
    const int wv = tid >> 6;
    const int lane = tid & 63;
    const int quad = lane >> 4;
    const int l16 = lane & 15;
    const int u = wv*16 + l16;
    for (int i = tid; i < PSEQ*90; i += 256) price_s[i] = price[(size_t)n0*90 + i];
    for (int i = tid; i < PSEQ*72; i += 256) { h_hi[i] = 0; h_lo[i] = 0; }
    float wir[3], wiz[3], win[3];
    #pragma unroll
    for (int k = 0; k < 3; k++) {
        wir[k] = Wi[k*G3 + u];
        wiz[k] = Wi[k*G3 + 64 + u];
        win[k] = Wi[k*G3 + 128 + u];
    }
    const float cbr = bi[u] + bh[u];
    const float cbz = bi[64+u] + bh[64+u];
    const float bin = bi[128+u];
    const float bhn = bh[128+u];
    short8_t bfh[2][3], bfl[2][3];
    #pragma unroll
    for (int kt = 0; kt < 2; kt++)
        #pragma unroll
        for (int g = 0; g < 3; g++) {
            size_t off = (((size_t)kt*NNT + (g*4 + wv))*64 + lane)*8;
            bfh[kt][g] = *(const short8_t*)(Whf_hi + off);
            bfl[kt][g] = *(const short8_t*)(Whf_lo + off);
        }
    float hprev[4] = {0.f,0.f,0.f,0.f}, sum[4] = {0.f,0.f,0.f,0.f};
    __syncthreads();
    for (int t = 0; t < Tq; t++) {
        short8_t ah[2], al[2];
        #pragma unroll
        for (int kt = 0; kt < 2; kt++) {
            int addr = l16*72 + kt*32 + quad*8;
            ah[kt] = *(const short8_t*)&h_hi[addr];
            al[kt] = *(const short8_t*)&h_lo[addr];
        }
        float4_t accr = {0.f,0.f,0.f,0.f}, accz = {0.f,0.f,0.f,0.f}, accn = {0.f,0.f,0.f,0.f};
        #pragma unroll
        for (int kt = 0; kt < 2; kt++) {
            accr = __builtin_amdgcn_mfma_f32_16x16x32_bf16(ah[kt], bfh[kt][0], accr, 0,0,0);
            accr = __builtin_amdgcn_mfma_f32_16x16x32_bf16(ah[kt], bfl[kt][0], accr, 0,0,0);
            accr = __builtin_amdgcn_mfma_f32_16x16x32_bf16(al[kt], bfh[kt][0], accr, 0,0,0);
            accz = __builtin_amdgcn_mfma_f32_16x16x32_bf16(ah[kt], bfh[kt][1], accz, 0,0,0);
            accz = __builtin_amdgcn_mfma_f32_16x16x32_bf16(ah[kt], bfl[kt][1], accz, 0,0,0);
            accz = __builtin_amdgcn_mfma_f32_16x16x32_bf16(al[kt], bfh[kt][1], accz, 0,0,0);
            accn = __builtin_amdgcn_mfma_f32_16x16x32_bf16(ah[kt], bfh[kt][2], accn, 0,0,0);
            accn = __builtin_amdgcn_mfma_f32_16x16x32_bf16(ah[kt], bfl[kt][2], accn, 0,0,0);
            accn = __builtin_amdgcn_mfma_f32_16x16x32_bf16(al[kt], bfh[kt][2], accn, 0,0,0);  // lo*hi (bugfix)
        }
        __syncthreads();   // A-frag reads done before h is rewritten
        #pragma unroll
        for (int r = 0; r < 4; r++) {
            const int s = quad*4 + r;
            float p0 = price_s[s*90 + t*3 + 0];
            float p1 = price_s[s*90 + t*3 + 1];
            float p2 = price_s[s*90 + t*3 + 2];
            float xr = fmaf(p2, wir[2], fmaf(p1, wir[1], fmaf(p0, wir[0], cbr)));
            float xz = fmaf(p2, wiz[2], fmaf(p1, wiz[1], fmaf(p0, wiz[0], cbz)));
            float xn = fmaf(p2, win[2], fmaf(p1, win[1], fmaf(p0, win[0], bin)));
            float rg = fsig(xr + accr[r]);
            float zg = fsig(xz + accz[r]);
            float ng = ftanh(xn + rg*(accn[r] + bhn));
            float h = (1.0f - zg)*ng + zg*hprev[r];
            hprev[r] = h; sum[r] += h;
            short hh = f32_to_bf16_rn(h);
            h_hi[s*72 + u] = hh;
            h_lo[s*72 + u] = f32_to_bf16_rn(h - bf16_to_f32(hh));
        }
        __syncthreads();   // h writes visible before next A-frag read
    }
    #pragma unroll
    for (int r = 0; r < 4; r++)
        xout[(size_t)(n0 + quad*4 + r)*Hq + u] = sum[r];
}

// ------------- tweet GRU: packed-row MFMA projection + MFMA recurrence ------
// v5: valid (s,t) rows packed contiguously (row = prefix[s]+t), m-tile loop
// gated at mt_hi = ceil(total/16) -> avg 1.73 of 3 tiles computed.
__global__ __launch_bounds__(256, 4)
void tweet_gru_kernel(const float* __restrict__ tweets,
                      const int* __restrict__ counts,
                      const short* __restrict__ Wf_hi, const short* __restrict__ Wf_lo,
                      const short* __restrict__ Wht_hi, const short* __restrict__ Wht_lo,
                      const float* __restrict__ bi, const float* __restrict__ bh,
                      float* __restrict__ news) {
    __shared__ __align__(16) char smem[XROWS*XGP*4];   // 31360 B
    __shared__ __align__(16) short rh_hi[16*72];
    __shared__ __align__(16) short rh_lo[16*72];
    __shared__ int len_s[TG];
    __shared__ int pref_s[TG+1];
    __shared__ int tmax_s;
    short* stg = (short*)smem;     // [2 bufs][hi | lo] planes
    float* xg  = (float*)smem;     // [XROWS][XGP] f32, aliases staging

    const int tid  = threadIdx.x;
    const int n0   = blockIdx.x * TG;
    const int wave = tid >> 6;
    const int lane = tid & 63;
    const int quad = lane >> 4;
    const int l16  = lane & 15;

    if (tid < TG) {
        int c = counts[n0 + tid];
        len_s[tid] = c < 0 ? 0 : (c > Kq ? Kq : c);
    }
    for (int i = tid; i < 16*72; i += 256) { rh_hi[i] = 0; rh_lo[i] = 0; }
    __syncthreads();
    if (tid == 0) {
        int p = 0;
        #pragma unroll
        for (int s = 0; s < TG; s++) { pref_s[s] = p; p += len_s[s]; }
        pref_s[TG] = p;
        int m01 = len_s[0] > len_s[1] ? len_s[0] : len_s[1];
        int m23 = len_s[2] > len_s[3] ? len_s[2] : len_s[3];
        tmax_s = m01 > m23 ? m01 : m23;
    }
    __syncthreads();
    const int total = pref_s[TG];          // live rows (0..40)
    const int mt_hi = (total + 15) >> 4;   // active m-tiles (0..3)

    // ---- hoisted staging descriptors (640 float4 items, stride 256) --------
    const float* gp[3];
    int lofs[3];
    bool val[3];
    #pragma unroll
    for (int j = 0; j < 3; j++) {
        const int ii = tid + j*256;
        const bool ok = ii < TG*Kq*(KC/4);        // < 640
        const int i = ok ? ii : 0;
        const int row = i >> 4;
        const int c4  = i & 15;
        const int s   = (row*205) >> 11;          // row/10 for row<48
        const int t   = row - s*10;
        val[j]  = ok && (t < len_s[s]);
        gp[j]   = tweets + (((size_t)(n0+s))*Kq + t)*TWq + c4*4;
        lofs[j] = (pref_s[s] + t)*XPITCH + c4*4;  // packed row slot
    }

    float4_t acc[3][3];   // [mt][ntl]
    #pragma unroll
    for (int a = 0; a < 3; a++)
        #pragma unroll
        for (int b = 0; b < 3; b++)
            acc[a][b] = (float4_t){0.f, 0.f, 0.f, 0.f};

    // ---- prologue: stage chunk 0 into buffer 0 ----
    #pragma unroll
    for (int j = 0; j < 3; j++) if (val[j]) {
        float4 v = *(const float4*)(gp[j]);
        float f[4] = {v.x, v.y, v.z, v.w};
        short hh[4], ll[4];
        #pragma unroll
        for (int q = 0; q < 4; q++) {
            short hi = f32_to_bf16_rn(f[q]);
            hh[q] = hi;
            ll[q] = f32_to_bf16_rn(f[q] - bf16_to_f32(hi));
        }
        *(short4*)&stg[lofs[j]]             = *(const short4*)hh;
        *(short4*)&stg[STG_PLANE + lofs[j]] = *(const short4*)ll;
    }
    __syncthreads();

    for (int ch = 0; ch < TWq/KC; ch++) {
        const int cur = ch & 1;
        // (1) issue next chunk's global loads early
        float4 v[3];
        if (ch < TWq/KC - 1) {
            #pragma unroll
            for (int j = 0; j < 3; j++) if (val[j])
                v[j] = *(const float4*)(gp[j] + (ch+1)*KC);
        }
        // (2) MFMA on current buffer, active m-tiles only
        const short* xh = stg + cur*STG_BUF;
        const short* xl = xh + STG_PLANE;
        #pragma unroll
        for (int ks = 0; ks < KC/32; ks++) {
            const int kt = ch*(KC/32) + ks;
            short8_t bh_[3], bl_[3];
            #pragma unroll
            for (int ntl = 0; ntl < 3; ntl++) {
                size_t off = (((size_t)kt*NNT + (wave*3 + ntl))*64 + lane)*8;
                bh_[ntl] = *(const short8_t*)(Wf_hi + off);
                bl_[ntl] = *(const short8_t*)(Wf_lo + off);
            }
            short8_t ah_[3], al_[3];
            #pragma unroll
            for (int mt = 0; mt < 3; mt++) if (mt < mt_hi) {
                int addr = (mt*16 + l16)*XPITCH + ks*32 + quad*8;
                ah_[mt] = *(const short8_t*)&xh[addr];
                al_[mt] = *(const short8_t*)&xl[addr];
            }
            #pragma unroll
            for (int mt = 0; mt < 3; mt++) if (mt < mt_hi)
                #pragma unroll
                for (int ntl = 0; ntl < 3; ntl++) {
                    acc[mt][ntl] = __builtin_amdgcn_mfma_f32_16x16x32_bf16(ah_[mt], bh_[ntl], acc[mt][ntl], 0, 0, 0);
                    acc[mt][ntl] = __builtin_amdgcn_mfma_f32_16x16x32_bf16(ah_[mt], bl_[ntl], acc[mt][ntl], 0, 0, 0);
                    acc[mt][ntl] = __builtin_amdgcn_mfma_f32_16x16x32_bf16(al_[mt], bh_[ntl], acc[mt][ntl], 0, 0, 0);
                }
        }
        // (3) convert + write next chunk into the other buffer
        if (ch < TWq/KC - 1) {
            short* yh = stg + (cur^1)*STG_BUF;
            short* yl = yh + STG_PLANE;
            #pragma unroll
            for (int j = 0; j < 3; j++) if (val[j]) {
                float f[4] = {v[j].x, v[j].y, v[j].z, v[j].w};
                short hh[4], ll[4];
                #pragma unroll
                for (int q = 0; q < 4; q++) {
                    short hi = f32_to_bf16_rn(f[q]);
                    hh[q] = hi;
                    ll[q] = f32_to_bf16_rn(f[q] - bf16_to_f32(hi));
                }
                *(short4*)&yh[lofs[j]] = *(const short4*)hh;
                *(short4*)&yl[lofs[j]] = *(const short4*)ll;
            }
        }
        __syncthreads();   // next buffer ready; current buffer reads done
    }

    // ---- epilogue: acc -> xg (packed rows < total) ----
    #pragma unroll
    for (int ntl = 0; ntl < 3; ntl++) {
        const int col = (wave*3 + ntl)*16 + l16;
        const float bic = bi[col];
        #pragma unroll
        for (int mt = 0; mt < 3; mt++) {
            const int row0 = mt*16 + quad*4;
            #pragma unroll
            for (int r2 = 0; r2 < 4; r2++)
                if (row0 + r2 < total)
                    xg[(row0 + r2)*XGP + col] = acc[mt][ntl][r2] + bic;
        }
    }

    // ---- recurrence via MFMA (gate-aligned) ----
    const int u = wave*16 + l16;
    short8_t tbh[2][3], tbl[2][3];
    #pragma unroll
    for (int kt = 0; kt < 2; kt++)
        #pragma unroll
        for (int g = 0; g < 3; g++) {
            size_t off = (((size_t)kt*NNT + (g*4 + wave))*64 + lane)*8;
            tbh[kt][g] = *(const short8_t*)(Wht_hi + off);
            tbl[kt][g] = *(const short8_t*)(Wht_lo + off);
        }
    const float bhr = bh[u];
    const float bhz = bh[64+u];
    const float bhn = bh[128+u];
    int lp[4], pr[4];
    #pragma unroll
    for (int r = 0; r < 4; r++) { lp[r] = len_s[r]; pr[r] = pref_s[r]; }
    float hprev[4] = {0.f,0.f,0.f,0.f}, sum[4] = {0.f,0.f,0.f,0.f};
    const int tmax = tmax_s;
    for (int t = 0; t < tmax; t++) {
        const int ha = l16*72;
        short8_t ah0 = *(const short8_t*)&rh_hi[ha + quad*8];
        short8_t ah1 = *(const short8_t*)&rh_hi[ha + 32 + quad*8];
        short8_t al0 = *(const short8_t*)&rh_lo[ha + quad*8];
        short8_t al1 = *(const short8_t*)&rh_lo[ha + 32 + quad*8];
        float4_t ar = {0.f,0.f,0.f,0.f}, az = {0.f,0.f,0.f,0.f}, an = {0.f,0.f,0.f,0.f};
        ar = __builtin_amdgcn_mfma_f32_16x16x32_bf16(ah0, tbh[0][0], ar, 0,0,0);
        ar = __builtin_amdgcn_mfma_f32_16x16x32_bf16(ah0, tbl[0][0], ar, 0,0,0);
        ar = __builtin_amdgcn_mfma_f32_16x16x32_bf16(al0, tbh[0][0], ar, 0,0,0);
        ar = __builtin_amdgcn_mfma_f32_16x16x32_bf16(ah1, tbh[1][0], ar, 0,0,0);
        ar = __builtin_amdgcn_mfma_f32_16x16x32_bf16(ah1, tbl[1][0], ar, 0,0,0);
        ar = __builtin_amdgcn_mfma_f32_16x16x32_bf16(al1, tbh[1][0], ar, 0,0,0);
        az = __builtin_amdgcn_mfma_f32_16x16x32_bf16(ah0, tbh[0][1], az, 0,0,0);
        az = __builtin_amdgcn_mfma_f32_16x16x32_bf16(ah0, tbl[0][1], az, 0,0,0);
        az = __builtin_amdgcn_mfma_f32_16x16x32_bf16(al0, tbh[0][1], az, 0,0,0);
        az = __builtin_amdgcn_mfma_f32_16x16x32_bf16(ah1, tbh[1][1], az, 0,0,0);
        az = __builtin_amdgcn_mfma_f32_16x16x32_bf16(ah1, tbl[1][1], az, 0,0,0);
        az = __builtin_amdgcn_mfma_f32_16x16x32_bf16(al1, tbh[1][1], az, 0,0,0);
        an = __builtin_amdgcn_mfma_f32_16x16x32_bf16(ah0, tbh[0][2], an, 0,0,0);
        an = __builtin_amdgcn_mfma_f32_16x16x32_bf16(ah0, tbl[0][2], an, 0,0,0);
        an = __builtin_amdgcn_mfma_f32_16x16x32_bf16(al0, tbh[0][2], an, 0,0,0);
        an = __builtin_amdgcn_mfma_f32_16x16x32_bf16(ah1, tbh[1][2], an, 0,0,0);
        an = __builtin_amdgcn_mfma_f32_16x16x32_bf16(ah1, tbl[1][2], an, 0,0,0);
        an = __builtin_amdgcn_mfma_f32_16x16x32_bf16(al1, tbh[1][2], an, 0,0,0);  // lo*hi (bugfix)
        __syncthreads();   // A-frag reads (and epilogue xg writes at t=0) done
        if (quad == 0) {
            #pragma unroll
            for (int r = 0; r < 4; r++) {
                if (t < lp[r]) {
                    const float* xr = &xg[(pr[r] + t)*XGP];
                    float rg = fsig(xr[u]        + ar[r] + bhr);
                    float zg = fsig(xr[Hq+u]     + az[r] + bhz);
                    float ng = ftanh(xr[2*Hq+u]  + rg*(an[r] + bhn));
                    float hn = (1.0f - zg)*ng + zg*hprev[r];
                    hprev[r] = hn; sum[r] += hn;
                    short hh = f32_to_bf16_rn(hn);
                    rh_hi[r*72 + u] = hh;
                    rh_lo[r*72 + u] = f32_to_bf16_rn(hn - bf16_to_f32(hh));
                }
            }
        }
        __syncthreads();   // h writes visible before next A-frag read
    }
    if (quad == 0) {
        #pragma unroll
        for (int r = 0; r < 4; r++)
            news[(size_t)(n0 + r)*Hq + u] = sum[r];
    }
}

// ---------------- date GRU: one block (192 thr) per sequence ----------------
__global__ __launch_bounds__(192)
void date_gru_kernel(const float* __restrict__ news,
                     const float* __restrict__ Wi, const float* __restrict__ Wh,
                     const float* __restrict__ bi, const float* __restrict__ bh,
                     float* __restrict__ text) {
    __shared__ __align__(16) float nw_s[Dq*Hq];
    __shared__ __align__(16) float h_s[Hq];
    __shared__ __align__(16) float xg_s[G3];
    __shared__ __align__(16) float hg_s[G3];
    const int n = blockIdx.x;
    const int g = threadIdx.x;
    for (int i = g; i < Dq*Hq; i += 192) nw_s[i] = news[(size_t)n*Dq*Hq + i];
    float wi[Hq], wh[Hq];
    #pragma unroll
    for (int j = 0; j < Hq; j++) { wi[j] = Wi[j*G3+g]; wh[j] = Wh[j*G3+g]; }
    const float big = bi[g], bhg = bh[g];
    if (g < Hq) h_s[g] = 0.0f;
    float hreg = 0.0f, sum = 0.0f;
    __syncthreads();
    for (int t = 0; t < Dq; t++) {
        float a0=0.f,a1=0.f,a2=0.f,a3=0.f, b0=0.f,b1=0.f,b2=0.f,b3=0.f;
        #pragma unroll
        for (int j = 0; j < Hq; j += 4) {
            float4 nv = *(const float4*)&nw_s[t*Hq + j];
            float4 hv = *(const float4*)&h_s[j];
            a0 = fmaf(nv.x, wi[j+0], a0);
            a1 = fmaf(nv.y, wi[j+1], a1);
            a2 = fmaf(nv.z, wi[j+2], a2);
            a3 = fmaf(nv.w, wi[j+3], a3);
            b0 = fmaf(hv.x, wh[j+0], b0);
            b1 = fmaf(hv.y, wh[j+1], b1);
            b2 = fmaf(hv.z, wh[j+2], b2);
            b3 = fmaf(hv.w, wh[j+3], b3);
        }
        xg_s[g] = big + ((a0+a1)+(a2+a3));
        hg_s[g] = bhg + ((b0+b1)+(b2+b3));
        __syncthreads();
        if (g < Hq) {
            float r  = fsig(xg_s[g]      + hg_s[g]);
            float z  = fsig(xg_s[Hq+g]   + hg_s[Hq+g]);
            float nn = ftanh(xg_s[2*Hq+g] + r*hg_s[2*Hq+g]);
            hreg = (1.0f - z)*nn + z*hreg;
            sum += hreg;
            h_s[g] = hreg;
        }
        __syncthreads();
    }
    if (g < Hq) text[(size_t)n*Hq + g] = sum;
}

// -------- bilinear via MFMA: C[n,k] = tanh(sum_ij P[n,ij] A2[k,ij] + b_k) ---
#define TP 68
#define XP 72
__global__ __launch_bounds__(256)
void bilinear_mfma_kernel(const float* __restrict__ text, const float* __restrict__ x,
                          const short* __restrict__ Bf_hi, const short* __restrict__ Bf_lo,
                          const float* __restrict__ bb, float* __restrict__ ft) {
    __shared__ __align__(16) float t_s[16*TP];
    __shared__ __align__(16) float x_s[16*XP];
    const int tid = threadIdx.x;
    const int n0 = blockIdx.x * 16;
    const int wv = tid >> 6, lane = tid & 63, quad = lane >> 4, l16 = lane & 15;
    for (int i = tid; i < 16*64; i += 256) {
        int r = i >> 6, c = i & 63;
        t_s[r*TP + c] = text[(size_t)(n0 + r)*Hq + c];
        x_s[r*XP + c] = x[(size_t)(n0 + r)*Hq + c];
    }
    float4_t acc = {0.f,0.f,0.f,0.f};
    __syncthreads();
    for (int kt = 0; kt < 128; kt++) {
        const int i  = kt >> 1;
        const int j0 = (kt & 1)*32 + quad*8;
        size_t boff = (((size_t)kt*4 + wv)*64 + lane)*8;
        short8_t bh_ = *(const short8_t*)(Bf_hi + boff);
        short8_t bl_ = *(const short8_t*)(Bf_lo + boff);
        float ti = t_s[l16*TP + i];
        float xv[8];
        *(float4*)&xv[0] = *(const float4*)&x_s[l16*XP + j0];
        *(float4*)&xv[4] = *(const float4*)&x_s[l16*XP + j0 + 4];
        short ph[8], pl[8];
        #pragma unroll
        for (int jj = 0; jj < 8; jj++) {
            float p = ti * xv[jj];
            short hi = f32_to_bf16_rn(p);
            ph[jj] = hi;
            pl[jj] = f32_to_bf16_rn(p - bf16_to_f32(hi));
        }
        short8_t ah = *(const short8_t*)ph;
        short8_t al = *(const short8_t*)pl;
        acc = __builtin_amdgcn_mfma_f32_16x16x32_bf16(ah, bh_, acc, 0,0,0);
        acc = __builtin_amdgcn_mfma_f32_16x16x32_bf16(ah, bl_, acc, 0,0,0);
        acc = __builtin_amdgcn_mfma_f32_16x16x32_bf16(al, bh_, acc, 0,0,0);
    }
    const int col = wv*16 + l16;
    const float bk = bb[col];
    #pragma unroll
    for (int r = 0; r < 4; r++) {
        int n = quad*4 + r;
        ft[(size_t)(n0 + n)*Hq + col] = ftanh(acc[r] + bk);
    }
}

// ------------------------------ head ----------------------------------------
__global__ __launch_bounds__(64)
void head_kernel(const float* __restrict__ ft,
                 const int* __restrict__ off, const int* __restrict__ sorted_src,
                 const float* __restrict__ gnn_W, const float* __restrict__ gnn_b,
                 const float* __restrict__ fc1_W, const float* __restrict__ fc1_b,
                 const float* __restrict__ ln1_g, const float* __restrict__ ln1_b,
                 const float* __restrict__ fc2_W, const float* __restrict__ fc2_b,
                 const float* __restrict__ ln2_g, const float* __restrict__ ln2_b,
                 const float* __restrict__ mlp_W1, const float* __restrict__ mlp_b1,
                 const float* __restrict__ mlp_W2, const float* __restrict__ mlp_b2,
                 float* __restrict__ out) {
    __shared__ __align__(16) float a_s[Hq];
    __shared__ __align__(16) float in_s[2*Hq];
    __shared__ __align__(16) float t_s[Hq];
    const int n = blockIdx.x;
    const int b = n / Sq;
    const int s = n - b*Sq;
    const int u = threadIdx.x;
    const int o0 = off[s], o1 = off[s+1];
    const float* ftb = ft + (size_t)b*Sq*Hq;
    float acc = 0.0f;
    for (int e = o0; e < o1; ++e)
        acc += ftb[(size_t)sorted_src[e]*Hq + u];
    const float denom = (o1 - o0) > 1 ? (float)(o1 - o0) : 1.0f;
    a_s[u]  = acc / denom;
    in_s[u] = ft[(size_t)n*Hq + u];
    __syncthreads();
    {
        float a0=0.f,a1=0.f,a2=0.f,a3=0.f;
        #pragma unroll
        for (int j = 0; j < Hq; j += 4) {
            a0 = fmaf(a_s[j+0], gnn_W[(j+0)*Hq + u], a0);
            a1 = fmaf(a_s[j+1], gnn_W[(j+1)*Hq + u], a1);
            a2 = fmaf(a_s[j+2], gnn_W[(j+2)*Hq + u], a2);
            a3 = fmaf(a_s[j+3], gnn_W[(j+3)*Hq + u], a3);
        }
        in_s[Hq+u] = ftanh(gnn_b[u] + ((a0+a1)+(a2+a3)));
    }
    __syncthreads();
    float v;
    {
        float a0=0.f,a1=0.f,a2=0.f,a3=0.f;
        #pragma unroll
        for (int j = 0; j < 2*Hq; j += 4) {
            a0 = fmaf(in_s[j+0], fc1_W[(j+0)*Hq + u], a0);
            a1 = fmaf(in_s[j+1], fc1_W[(j+1)*Hq + u], a1);
            a2 = fmaf(in_s[j+2], fc1_W[(j+2)*Hq + u], a2);
            a3 = fmaf(in_s[j+3], fc1_W[(j+3)*Hq + u], a3);
        }
        v = fc1_b[u] + ((a0+a1)+(a2+a3));
        float m = wave_sum64(v) * (1.0f/Hq);
        float d = v - m;
        float var = wave_sum64(d*d) * (1.0f/Hq);
        v = fmaxf(d * rsqrtf(var + 1e-5f) * ln1_g[u] + ln1_b[u], 0.0f);
    }
    t_s[u] = v;
    __syncthreads();
    {
        float a0=0.f,a1=0.f,a2=0.f,a3=0.f;
        #pragma unroll
        for (int j = 0; j < Hq; j += 4) {
            a0 = fmaf(t_s[j+0], fc2_W[(j+0)*Hq + u], a0);
            a1 = fmaf(t_s[j+1], fc2_W[(j+1)*Hq + u], a1);
            a2 = fmaf(t_s[j+2], fc2_W[(j+2)*Hq + u], a2);
            a3 = fmaf(t_s[j+3], fc2_W[(j+3)*Hq + u], a3);
        }
        v = fc2_b[u] + ((a0+a1)+(a2+a3));
        float m = wave_sum64(v) * (1.0f/Hq);
        float d = v - m;
        float var = wave_sum64(d*d) * (1.0f/Hq);
        v = fmaxf(d * rsqrtf(var + 1e-5f) * ln2_g[u] + ln2_b[u], 0.0f);
    }
    __syncthreads();
    a_s[u] = v;
    __syncthreads();
    {
        float a0=0.f,a1=0.f,a2=0.f,a3=0.f;
        #pragma unroll
        for (int j = 0; j < Hq; j += 4) {
            a0 = fmaf(a_s[j+0], mlp_W1[(j+0)*Hq + u], a0);
            a1 = fmaf(a_s[j+1], mlp_W1[(j+1)*Hq + u], a1);
            a2 = fmaf(a_s[j+2], mlp_W1[(j+2)*Hq + u], a2);
            a3 = fmaf(a_s[j+3], mlp_W1[(j+3)*Hq + u], a3);
        }
        v = fmaxf(mlp_b1[u] + ((a0+a1)+(a2+a3)), 0.0f);
    }
    float p = wave_sum64(v * mlp_W2[u]);
    if (u == 0) out[n] = p + mlp_b2[0];
}

extern "C" void kernel_launch(void* const* d_in, const int* in_sizes, int n_in,
                              void* d_out, int out_size, void* d_ws, size_t ws_size,
                              hipStream_t stream) {
    (void)in_sizes; (void)n_in; (void)out_size; (void)ws_size;
    const float* price  = (const float*)d_in[0];
    const float* tweets = (const float*)d_in[1];
    const int*   counts = (const int*)d_in[2];
    const int*   ei     = (const int*)d_in[3];
    const float* pg_Wi = (const float*)d_in[5];
    const float* pg_Wh = (const float*)d_in[6];
    const float* pg_bi = (const float*)d_in[7];
    const float* pg_bh = (const float*)d_in[8];
    const float* tg_Wi = (const float*)d_in[9];
    const float* tg_Wh = (const float*)d_in[10];
    const float* tg_bi = (const float*)d_in[11];
    const float* tg_bh = (const float*)d_in[12];
    const float* dg_Wi = (const float*)d_in[13];
    const float* dg_Wh = (const float*)d_in[14];
    const float* dg_bi = (const float*)d_in[15];
    const float* dg_bh = (const float*)d_in[16];
    const float* bil_A = (const float*)d_in[17];
    const float* bil_b = (const float*)d_in[18];
    const float* gnn_W = (const float*)d_in[19];
    const float* gnn_b = (const float*)d_in[20];
    const float* fc1_W = (const float*)d_in[21];
    const float* fc1_b = (const float*)d_in[22];
    const float* ln1_g = (const float*)d_in[23];
    const float* ln1_b = (const float*)d_in[24];
    const float* fc2_W = (const float*)d_in[25];
    const float* fc2_b = (const float*)d_in[26];
    const float* ln2_g = (const float*)d_in[27];
    const float* ln2_b = (const float*)d_in[28];
    const float* mlp_W1 = (const float*)d_in[29];
    const float* mlp_b1 = (const float*)d_in[30];
    const float* mlp_W2 = (const float*)d_in[31];
    const float* mlp_b2 = (const float*)d_in[32];

    float* ws      = (float*)d_ws;
    float* x_price = ws;                   // 4000*64   = 256000
    float* news    = ws + 256000;          // 20000*64  = 1280000
    float* text    = ws + 1536000;         // 4000*64
    float* ft      = ws + 1792000;         // 4000*64
    int*   off     = (int*)(ws + 2048000); // 501 (pad 512)
    int*   sorted  = off + 512;            // 8000
    short* Wf_hi   = (short*)(ws + 2304512);           // 98304 shorts
    short* Wf_lo   = Wf_hi  + 98304;
    short* Whp_hi  = Wf_lo  + 98304;                   // 12288
    short* Whp_lo  = Whp_hi + 12288;
    short* Bf_hi   = Whp_lo + 12288;                   // 262144
    short* Bf_lo   = Bf_hi  + 262144;
    short* Wht_hi  = Bf_lo  + 262144;                  // 12288
    short* Wht_lo  = Wht_hi + 12288;

    csr_kernel<<<1, 512, 0, stream>>>(ei, off, sorted);
    prep_all_kernel<<<PREP_BLOCKS, 64, 0, stream>>>(
        tg_Wi, pg_Wh, tg_Wh, bil_A,
        Wf_hi, Wf_lo, Whp_hi, Whp_lo, Wht_hi, Wht_lo, Bf_hi, Bf_lo);

    price_gru_mfma_kernel<<<NS/PSEQ, 256, 0, stream>>>(price, pg_Wi, Whp_hi, Whp_lo,
                                                       pg_bi, pg_bh, x_price);
    tweet_gru_kernel<<<NTt/TG, 256, 0, stream>>>(tweets, counts, Wf_hi, Wf_lo,
                                                 Wht_hi, Wht_lo, tg_bi, tg_bh, news);
    date_gru_kernel<<<NS, 192, 0, stream>>>(news, dg_Wi, dg_Wh, dg_bi, dg_bh, text);
    bilinear_mfma_kernel<<<NS/16, 256, 0, stream>>>(text, x_price, Bf_hi, Bf_lo, bil_b, ft);
    head_kernel<<<NS, 64, 0, stream>>>(ft, off, sorted,
                                       gnn_W, gnn_b, fc1_W, fc1_b, ln1_g, ln1_b,
                                       fc2_W, fc2_b, ln2_g, ln2_b,
                                       mlp_W1, mlp_b1, mlp_W2, mlp_b2,
                                       (float*)d_out);
}